// Round 1
// baseline (1434.410 us; speedup 1.0000x reference)
//
#include <hip/hip_runtime.h>
#include <math.h>

#define BATCH 16
#define CH    128
#define HGT   56
#define WID   56
#define NPIX  (BATCH*HGT*WID)   // 50176
#define NQKV  384
#define NWIN  7
#define P2    49
#define TOPK  4
#define ATT_SCALE 0.088388347648318447f   // 128^-0.5

// ---------------------------------------------------------------------------
// K1: x(NCHW) -> xh(NHWC) = x + dwconv3x3(x)
// grid (C, B), 256 threads; per-block one (b,c) plane (12.5 KB, L1-resident)
// ---------------------------------------------------------------------------
__global__ __launch_bounds__(256) void k_posconv(const float* __restrict__ x,
    const float* __restrict__ pw, const float* __restrict__ pb,
    float* __restrict__ xh) {
  int c = blockIdx.x, b = blockIdx.y;
  const float* xp = x + ((size_t)(b*CH + c))*(HGT*WID);
  float w[9];
#pragma unroll
  for (int i = 0; i < 9; i++) w[i] = pw[c*9 + i];
  float bias = pb[c];
  float* xhb = xh + (size_t)b*HGT*WID*CH + c;
  for (int pix = threadIdx.x; pix < HGT*WID; pix += 256) {
    int h = pix / WID, wv = pix - h*WID;
    float s = bias + xp[pix];
#pragma unroll
    for (int dy = 0; dy < 3; dy++) {
      int hy = h + dy - 1; if ((unsigned)hy >= HGT) continue;
#pragma unroll
      for (int dx = 0; dx < 3; dx++) {
        int wx = wv + dx - 1; if ((unsigned)wx >= WID) continue;
        s += xp[hy*WID + wx] * w[dy*3 + dx];
      }
    }
    xhb[(size_t)pix*CH] = s;
  }
}

// ---------------------------------------------------------------------------
// K2/K8: LN over C=128 then GEMM [64pix x 128] @ [128 x 384] (+bias, opt GELU)
// wave-broadcast GEMM: lane=pixel row (a from LDS, 2-way banks via stride 129),
// weight slice wave-uniform (LDS broadcast b128), 32 acc/lane.
// LDS: 33KB a-tile + 64KB W-chunk -> 1 block/CU.
// ---------------------------------------------------------------------------
__global__ __launch_bounds__(256) void k_ln_gemm384(const float* __restrict__ in,
    const float* __restrict__ g, const float* __restrict__ be,
    const float* __restrict__ Wm, const float* __restrict__ bias,
    float* __restrict__ out, int do_gelu) {
  __shared__ float y[64*129];
  __shared__ float Wc[128*128];
  size_t base = (size_t)blockIdx.x * 64;   // pixel base
  const float* src = in + base*CH;
  for (int i = threadIdx.x; i < 64*32; i += 256) {
    int r = i >> 5, cq = i & 31;
    float4 v = ((const float4*)src)[(size_t)r*32 + cq];
    float* dst = &y[r*129 + cq*4];
    dst[0] = v.x; dst[1] = v.y; dst[2] = v.z; dst[3] = v.w;
  }
  __syncthreads();
  { // LayerNorm: 4 threads per pixel row
    int j = threadIdx.x & 3, r = threadIdx.x >> 2;
    float s = 0.f, ss = 0.f, vals[32];
#pragma unroll
    for (int i = 0; i < 32; i++) {
      float v = y[r*129 + j*32 + i];
      vals[i] = v; s += v; ss += v*v;
    }
    s += __shfl_xor(s, 1); ss += __shfl_xor(ss, 1);
    s += __shfl_xor(s, 2); ss += __shfl_xor(ss, 2);
    float m  = s * (1.f/128.f);
    float var = ss * (1.f/128.f) - m*m;
    float rs = rsqrtf(var + 1e-6f);
#pragma unroll
    for (int i = 0; i < 32; i++) {
      int c = j*32 + i;
      y[r*129 + c] = (vals[i] - m) * rs * g[c] + be[c];
    }
  }
  __syncthreads();
  int wv = threadIdx.x >> 6, lane = threadIdx.x & 63;
  int n0 = wv*32;
  for (int chunk = 0; chunk < 3; chunk++) {
    for (int i = threadIdx.x; i < 128*32; i += 256) {
      int k = i >> 5, nq = i & 31;
      ((float4*)Wc)[i] = ((const float4*)(Wm + (size_t)k*NQKV + chunk*128))[nq];
    }
    __syncthreads();
    float acc[32];
#pragma unroll
    for (int i = 0; i < 32; i++) acc[i] = 0.f;
    const float* yr = &y[lane*129];
#pragma unroll 4
    for (int k = 0; k < 128; k++) {
      float a = yr[k];
      const float4* wr = (const float4*)&Wc[k*128 + n0];
#pragma unroll
      for (int q = 0; q < 8; q++) {
        float4 wq = wr[q];
        acc[q*4+0] += a*wq.x; acc[q*4+1] += a*wq.y;
        acc[q*4+2] += a*wq.z; acc[q*4+3] += a*wq.w;
      }
    }
    float* op = out + (base + lane)*NQKV + chunk*128 + n0;
#pragma unroll
    for (int i = 0; i < 32; i++) {
      float v = acc[i] + bias[chunk*128 + n0 + i];
      if (do_gelu) v = 0.5f * v * (1.f + erff(v * 0.70710678118654752f));
      acc[i] = v;
    }
#pragma unroll
    for (int q = 0; q < 8; q++)
      ((float4*)op)[q] = make_float4(acc[q*4], acc[q*4+1], acc[q*4+2], acc[q*4+3]);
    __syncthreads();
  }
}

// ---------------------------------------------------------------------------
// K3: window means of q (cols 0..127) and k (cols 128..255)
// grid = B*P2 blocks, 256 threads (one channel each)
// ---------------------------------------------------------------------------
__global__ __launch_bounds__(256) void k_winmean(const float* __restrict__ qkv,
    float* __restrict__ qwin, float* __restrict__ kwin) {
  int bp = blockIdx.x; int b = bp / P2, p = bp % P2;
  int wy = p / NWIN, wx = p % NWIN;
  int c = threadIdx.x;
  float s = 0.f;
  for (int pix = 0; pix < 64; pix++) {
    int ir = pix >> 3, iw = pix & 7;
    int hg = wy*8 + ir, wg = wx*8 + iw;
    s += qkv[(((size_t)b*HGT + hg)*WID + wg)*NQKV + c];
  }
  s *= (1.f/64.f);
  if (c < 128) qwin[(size_t)bp*128 + c] = s;
  else         kwin[(size_t)bp*128 + (c - 128)] = s;
}

// ---------------------------------------------------------------------------
// K4: routing logits (49x49 per image) + top-4 (lowest-index tie-break)
// grid = B, 64 threads (lane = query window)
// ---------------------------------------------------------------------------
__global__ __launch_bounds__(64) void k_topk(const float* __restrict__ qwin,
    const float* __restrict__ kwin, int* __restrict__ idx) {
  int b = blockIdx.x;
  int p = threadIdx.x;
  float logits[P2];
#pragma unroll
  for (int q = 0; q < P2; q++) logits[q] = 0.f;
  const float* qp = qwin + ((size_t)b*P2 + (p < P2 ? p : 0))*128;
  const float* kp = kwin + (size_t)b*P2*128;
  for (int cc = 0; cc < 32; cc++) {
    float4 qv = ((const float4*)qp)[cc];
#pragma unroll
    for (int q = 0; q < P2; q++) {
      float4 kv = ((const float4*)(kp + q*128))[cc];
      logits[q] += qv.x*kv.x + qv.y*kv.y + qv.z*kv.z + qv.w*kv.w;
    }
  }
  if (p < P2) {
    unsigned long long used = 0ULL;
    for (int t = 0; t < TOPK; t++) {
      float best = -1e30f; int bi = 0;
#pragma unroll
      for (int q = 0; q < P2; q++) {
        bool ok = !((used >> q) & 1ULL);
        if (ok && logits[q] > best) { best = logits[q]; bi = q; }
      }
      used |= 1ULL << bi;
      idx[((size_t)b*P2 + p)*TOPK + t] = bi;
    }
  }
}

// ---------------------------------------------------------------------------
// K5: gathered window attention. grid = B*P2, block 256 = 4 waves (1 head each),
// lane = query pixel. Online softmax per row; k/v for one selected window
// (all heads) staged per round in LDS (64KB -> 2 blocks/CU).
// ---------------------------------------------------------------------------
__global__ __launch_bounds__(256) void k_attn(const float* __restrict__ qkv,
    const int* __restrict__ idx, float* __restrict__ o) {
  __shared__ float kld[64*128];
  __shared__ float vld[64*128];
  int bp = blockIdx.x; int b = bp / P2, p = bp % P2;
  int wy = p / NWIN, wx = p % NWIN;
  int head = threadIdx.x >> 6, lane = threadIdx.x & 63;
  int ir = lane >> 3, iw = lane & 7;
  size_t pixoff = (((size_t)b*HGT + wy*8 + ir)*WID + wx*8 + iw)*NQKV;
  float qreg[32];
  {
    const float4* qp = (const float4*)(qkv + pixoff + head*32);
#pragma unroll
    for (int i = 0; i < 8; i++) {
      float4 v = qp[i];
      qreg[4*i] = v.x; qreg[4*i+1] = v.y; qreg[4*i+2] = v.z; qreg[4*i+3] = v.w;
    }
  }
  float m = -1e30f, l = 0.f;
  float oacc[32];
#pragma unroll
  for (int i = 0; i < 32; i++) oacc[i] = 0.f;

  for (int r = 0; r < TOPK; r++) {
    int win = idx[(size_t)bp*TOPK + r];
    int sy = win / NWIN, sx = win % NWIN;
    __syncthreads();
    for (int i = threadIdx.x; i < 64*32; i += 256) {
      int key = i >> 5, cq = i & 31;
      int kr = key >> 3, kw = key & 7;
      size_t po = (((size_t)b*HGT + sy*8 + kr)*WID + sx*8 + kw)*NQKV;
      ((float4*)kld)[i] = ((const float4*)(qkv + po + 128))[cq];
      ((float4*)vld)[i] = ((const float4*)(qkv + po + 256))[cq];
    }
    __syncthreads();
    for (int kc = 0; kc < 64; kc += 8) {
      float s[8];
#pragma unroll
      for (int j = 0; j < 8; j++) {
        const float4* kp = (const float4*)&kld[(kc+j)*128 + head*32];
        float acc = 0.f;
#pragma unroll
        for (int dq = 0; dq < 8; dq++) {
          float4 kv = kp[dq];
          acc += qreg[4*dq]*kv.x + qreg[4*dq+1]*kv.y + qreg[4*dq+2]*kv.z + qreg[4*dq+3]*kv.w;
        }
        s[j] = acc * ATT_SCALE;
      }
      float mc = s[0];
#pragma unroll
      for (int j = 1; j < 8; j++) mc = fmaxf(mc, s[j]);
      float mn = fmaxf(m, mc);
      float corr = __expf(m - mn);
      l *= corr;
#pragma unroll
      for (int i = 0; i < 32; i++) oacc[i] *= corr;
      m = mn;
#pragma unroll
      for (int j = 0; j < 8; j++) {
        float pex = __expf(s[j] - m);
        l += pex;
        const float4* vp = (const float4*)&vld[(kc+j)*128 + head*32];
#pragma unroll
        for (int dq = 0; dq < 8; dq++) {
          float4 vv = vp[dq];
          oacc[4*dq]   += pex*vv.x; oacc[4*dq+1] += pex*vv.y;
          oacc[4*dq+2] += pex*vv.z; oacc[4*dq+3] += pex*vv.w;
        }
      }
    }
  }
  float inv = 1.f / l;
  float* op = o + (pixoff / NQKV)*CH + head*32;
#pragma unroll
  for (int q = 0; q < 8; q++)
    ((float4*)op)[q] = make_float4(oacc[q*4]*inv, oacc[q*4+1]*inv,
                                   oacc[q*4+2]*inv, oacc[q*4+3]*inv);
}

// ---------------------------------------------------------------------------
// K6: o += dwconv5x5(v) + lepe_b; v = qkv cols [256,384). grid (H, B), 256 thr
// ---------------------------------------------------------------------------
__global__ __launch_bounds__(256) void k_lepe(const float* __restrict__ qkv,
    const float* __restrict__ lw, const float* __restrict__ lb,
    float* __restrict__ o) {
  int h = blockIdx.x, b = blockIdx.y;
  int c = threadIdx.x & 127, wi = threadIdx.x >> 7;
  float w[25];
#pragma unroll
  for (int i = 0; i < 25; i++) w[i] = lw[c*25 + i];
  float bias = lb[c];
  for (int w0 = wi; w0 < WID; w0 += 2) {
    float s = bias;
#pragma unroll
    for (int dy = 0; dy < 5; dy++) {
      int hy = h + dy - 2; if ((unsigned)hy >= HGT) continue;
#pragma unroll
      for (int dx = 0; dx < 5; dx++) {
        int wx = w0 + dx - 2; if ((unsigned)wx >= WID) continue;
        s += qkv[(((size_t)b*HGT + hy)*WID + wx)*NQKV + 256 + c] * w[dy*5 + dx];
      }
    }
    size_t oi = (((size_t)b*HGT + h)*WID + w0)*CH + c;
    o[oi] += s;
  }
}

// ---------------------------------------------------------------------------
// K7: xh += (o+lepe) @ wo_w + wo_b   (M=NPIX, K=128, N=128), in-place residual
// ---------------------------------------------------------------------------
__global__ __launch_bounds__(256) void k_wo(const float* __restrict__ in,
    const float* __restrict__ Wm, const float* __restrict__ bias,
    float* __restrict__ xh) {
  __shared__ float a[64*129];
  __shared__ float Wc[128*128];
  size_t base = (size_t)blockIdx.x * 64;
  const float* src = in + base*CH;
  for (int i = threadIdx.x; i < 64*32; i += 256) {
    int r = i >> 5, cq = i & 31;
    float4 v = ((const float4*)src)[(size_t)r*32 + cq];
    float* dst = &a[r*129 + cq*4];
    dst[0] = v.x; dst[1] = v.y; dst[2] = v.z; dst[3] = v.w;
  }
  for (int i = threadIdx.x; i < 128*32; i += 256)
    ((float4*)Wc)[i] = ((const float4*)Wm)[i];
  __syncthreads();
  int wv = threadIdx.x >> 6, lane = threadIdx.x & 63;
  int n0 = wv*32;
  float acc[32];
#pragma unroll
  for (int i = 0; i < 32; i++) acc[i] = 0.f;
  const float* ar = &a[lane*129];
#pragma unroll 4
  for (int k = 0; k < 128; k++) {
    float av = ar[k];
    const float4* wr = (const float4*)&Wc[k*128 + n0];
#pragma unroll
    for (int q = 0; q < 8; q++) {
      float4 wq = wr[q];
      acc[q*4+0] += av*wq.x; acc[q*4+1] += av*wq.y;
      acc[q*4+2] += av*wq.z; acc[q*4+3] += av*wq.w;
    }
  }
  float* xp = xh + (base + lane)*CH + n0;
#pragma unroll
  for (int q = 0; q < 8; q++) {
    float4 xv = ((float4*)xp)[q];
    ((float4*)xp)[q] = make_float4(xv.x + acc[q*4]   + bias[n0+q*4],
                                   xv.y + acc[q*4+1] + bias[n0+q*4+1],
                                   xv.z + acc[q*4+2] + bias[n0+q*4+2],
                                   xv.w + acc[q*4+3] + bias[n0+q*4+3]);
  }
}

// ---------------------------------------------------------------------------
// K9: out(NCHW) = xh + hidden @ mlp_w2 + mlp_b2  (M=NPIX, K=384, N=128)
// ---------------------------------------------------------------------------
__global__ __launch_bounds__(256) void k_mlp2(const float* __restrict__ hid,
    const float* __restrict__ Wm, const float* __restrict__ bias,
    const float* __restrict__ xh, float* __restrict__ out) {
  __shared__ float a[64*129];
  __shared__ float Wc[128*128];
  size_t base = (size_t)blockIdx.x * 64;
  int wv = threadIdx.x >> 6, lane = threadIdx.x & 63;
  int n0 = wv*32;
  float acc[32];
#pragma unroll
  for (int i = 0; i < 32; i++) acc[i] = 0.f;
  for (int kc = 0; kc < 3; kc++) {
    __syncthreads();
    for (int i = threadIdx.x; i < 64*32; i += 256) {
      int r = i >> 5, cq = i & 31;
      float4 v = ((const float4*)(hid + (base + r)*NQKV + kc*128))[cq];
      float* dst = &a[r*129 + cq*4];
      dst[0] = v.x; dst[1] = v.y; dst[2] = v.z; dst[3] = v.w;
    }
    for (int i = threadIdx.x; i < 128*32; i += 256) {
      int k = i >> 5, nq = i & 31;
      ((float4*)Wc)[i] = ((const float4*)(Wm + (size_t)(kc*128 + k)*CH))[nq];
    }
    __syncthreads();
    const float* ar = &a[lane*129];
#pragma unroll 4
    for (int k = 0; k < 128; k++) {
      float av = ar[k];
      const float4* wr = (const float4*)&Wc[k*128 + n0];
#pragma unroll
      for (int q = 0; q < 8; q++) {
        float4 wq = wr[q];
        acc[q*4+0] += av*wq.x; acc[q*4+1] += av*wq.y;
        acc[q*4+2] += av*wq.z; acc[q*4+3] += av*wq.w;
      }
    }
  }
  size_t pig = base + lane;
  int b = (int)(pig / (HGT*WID));
  int sp = (int)(pig % (HGT*WID));
  const float* xp = xh + pig*CH + n0;
  float* op = out + ((size_t)b*CH + n0)*(HGT*WID) + sp;
#pragma unroll
  for (int i = 0; i < 32; i++)
    op[(size_t)i*(HGT*WID)] = acc[i] + bias[n0 + i] + xp[i];
}

// ---------------------------------------------------------------------------
extern "C" void kernel_launch(void* const* d_in, const int* in_sizes, int n_in,
                              void* d_out, int out_size, void* d_ws, size_t ws_size,
                              hipStream_t stream) {
  const float* x      = (const float*)d_in[0];
  const float* pos_w  = (const float*)d_in[1];
  const float* pos_b  = (const float*)d_in[2];
  const float* ln1_g  = (const float*)d_in[3];
  const float* ln1_b  = (const float*)d_in[4];
  const float* qkv_w  = (const float*)d_in[5];
  const float* qkv_b  = (const float*)d_in[6];
  const float* lepe_w = (const float*)d_in[7];
  const float* lepe_b = (const float*)d_in[8];
  const float* wo_w   = (const float*)d_in[9];
  const float* wo_b   = (const float*)d_in[10];
  const float* ln2_g  = (const float*)d_in[11];
  const float* ln2_b  = (const float*)d_in[12];
  const float* mlp_w1 = (const float*)d_in[13];
  const float* mlp_b1 = (const float*)d_in[14];
  const float* mlp_w2 = (const float*)d_in[15];
  const float* mlp_b2 = (const float*)d_in[16];

  float* ws   = (float*)d_ws;
  float* xh   = ws;                          // NPIX*128
  float* qkv  = xh  + (size_t)NPIX*CH;       // NPIX*384
  float* o    = qkv + (size_t)NPIX*NQKV;     // NPIX*128
  float* qwin = o   + (size_t)NPIX*CH;       // B*49*128
  float* kwin = qwin + (size_t)BATCH*P2*128; // B*49*128
  int*   idx  = (int*)(kwin + (size_t)BATCH*P2*128); // B*49*4
  float* hid  = qkv;                         // reuse qkv buffer for MLP hidden

  k_posconv<<<dim3(CH, BATCH), 256, 0, stream>>>(x, pos_w, pos_b, xh);
  k_ln_gemm384<<<NPIX/64, 256, 0, stream>>>(xh, ln1_g, ln1_b, qkv_w, qkv_b, qkv, 0);
  k_winmean<<<BATCH*P2, 256, 0, stream>>>(qkv, qwin, kwin);
  k_topk<<<BATCH, 64, 0, stream>>>(qwin, kwin, idx);
  k_attn<<<BATCH*P2, 256, 0, stream>>>(qkv, idx, o);
  k_lepe<<<dim3(HGT, BATCH), 256, 0, stream>>>(qkv, lepe_w, lepe_b, o);
  k_wo<<<NPIX/64, 256, 0, stream>>>(o, wo_w, wo_b, xh);
  k_ln_gemm384<<<NPIX/64, 256, 0, stream>>>(xh, ln2_g, ln2_b, mlp_w1, mlp_b1, hid, 1);
  k_mlp2<<<NPIX/64, 256, 0, stream>>>(hid, mlp_w2, mlp_b2, xh, (float*)d_out);
}

// Round 2
// 854.049 us; speedup vs baseline: 1.6795x; 1.6795x over previous
//
#include <hip/hip_runtime.h>
#include <math.h>

#define BATCH 16
#define CH    128
#define HGT   56
#define WID   56
#define NPIX  (BATCH*HGT*WID)   // 50176
#define NQKV  384
#define NWIN  7
#define P2    49
#define TOPK  4
#define ATT_SCALE 0.088388347648318447f   // 128^-0.5

typedef __attribute__((ext_vector_type(8))) short short8;
typedef __attribute__((ext_vector_type(4))) float float4v;

static __device__ __forceinline__ unsigned short f2bf(float f) {
  unsigned u = __float_as_uint(f);
  u += 0x7fffu + ((u >> 16) & 1u);   // round-to-nearest-even
  return (unsigned short)(u >> 16);
}

// ---------------------------------------------------------------------------
// K0: weight prep — convert to bf16 and transpose to [N][K] layout.
// grid 1024 x 128 threads. segments: qkv(384), wo(128), mlp1(384), mlp2(128)
// ---------------------------------------------------------------------------
__global__ __launch_bounds__(128) void k_prep(
    const float* __restrict__ qkv_w, const float* __restrict__ wo_w,
    const float* __restrict__ mlp_w1, const float* __restrict__ mlp_w2,
    unsigned short* __restrict__ Wq, unsigned short* __restrict__ Wo,
    unsigned short* __restrict__ W1, unsigned short* __restrict__ W2) {
  int bx = blockIdx.x, t = threadIdx.x;
  if (bx < 384) {
    int n = bx;
    Wq[n*128 + t] = f2bf(qkv_w[(size_t)t*384 + n]);
  } else if (bx < 512) {
    int n = bx - 384;
    Wo[n*128 + t] = f2bf(wo_w[(size_t)t*128 + n]);
  } else if (bx < 896) {
    int n = bx - 512;
    W1[n*128 + t] = f2bf(mlp_w1[(size_t)t*384 + n]);
  } else {
    int n = bx - 896;
    for (int k = t; k < 384; k += 128)
      W2[n*384 + k] = f2bf(mlp_w2[(size_t)k*128 + n]);
  }
}

// ---------------------------------------------------------------------------
// K1: x(NCHW) -> xh(NHWC) = x + dwconv3x3(x)
// ---------------------------------------------------------------------------
__global__ __launch_bounds__(256) void k_posconv(const float* __restrict__ x,
    const float* __restrict__ pw, const float* __restrict__ pb,
    float* __restrict__ xh) {
  int c = blockIdx.x, b = blockIdx.y;
  const float* xp = x + ((size_t)(b*CH + c))*(HGT*WID);
  float w[9];
#pragma unroll
  for (int i = 0; i < 9; i++) w[i] = pw[c*9 + i];
  float bias = pb[c];
  float* xhb = xh + (size_t)b*HGT*WID*CH + c;
  for (int pix = threadIdx.x; pix < HGT*WID; pix += 256) {
    int h = pix / WID, wv = pix - h*WID;
    float s = bias + xp[pix];
#pragma unroll
    for (int dy = 0; dy < 3; dy++) {
      int hy = h + dy - 1; if ((unsigned)hy >= HGT) continue;
#pragma unroll
      for (int dx = 0; dx < 3; dx++) {
        int wx = wv + dx - 1; if ((unsigned)wx >= WID) continue;
        s += xp[hy*WID + wx] * w[dy*3 + dx];
      }
    }
    xhb[(size_t)pix*CH] = s;
  }
}

// ---------------------------------------------------------------------------
// K2/K8: fused LN + MFMA GEMM. M-tile 128, N=384 (3 chunks of 128), K=128.
// 4 waves, each a 64x64 subtile (4x4 frags of 16x16x32 bf16 MFMA).
// A: LN(in) -> bf16 LDS [128][136]; B: pre-transposed bf16 [N][K] global.
// ---------------------------------------------------------------------------
__global__ __launch_bounds__(256, 2) void k_ln_gemm_mfma(
    const float* __restrict__ in, const float* __restrict__ g,
    const float* __restrict__ be, const unsigned short* __restrict__ Wt,
    const float* __restrict__ bias, float* __restrict__ out, int do_gelu) {
  __shared__ __align__(16) unsigned short aL[128*136];
  __shared__ __align__(16) unsigned short bL[128*136];
  size_t base = (size_t)blockIdx.x * 128;
  int t = threadIdx.x;
  { // ---- LN + A-stage: threads 2r, 2r+1 handle row r halves ----
    int r = t >> 1, half = t & 1;
    const float4* src = (const float4*)(in + (base + r)*CH + half*64);
    float v[64];
    float s = 0.f, ss = 0.f;
#pragma unroll
    for (int i = 0; i < 16; i++) {
      float4 f = src[i];
      v[4*i] = f.x; v[4*i+1] = f.y; v[4*i+2] = f.z; v[4*i+3] = f.w;
      s += f.x + f.y + f.z + f.w;
      ss += f.x*f.x + f.y*f.y + f.z*f.z + f.w*f.w;
    }
    s += __shfl_xor(s, 1); ss += __shfl_xor(ss, 1);
    float m  = s * (1.f/128.f);
    float var = ss * (1.f/128.f) - m*m;
    float rs = rsqrtf(var + 1e-6f);
    union { unsigned short us[8]; int4 v4; } pk;
#pragma unroll
    for (int c8 = 0; c8 < 8; c8++) {
#pragma unroll
      for (int j = 0; j < 8; j++) {
        int ch = half*64 + c8*8 + j;
        pk.us[j] = f2bf((v[c8*8 + j] - m) * rs * g[ch] + be[ch]);
      }
      *(int4*)&aL[r*136 + half*64 + c8*8] = pk.v4;
    }
  }
  int wid = t >> 6, lane = t & 63;
  int ln = lane & 15, q = lane >> 4;
  int wr = (wid >> 1)*64, wc = (wid & 1)*64;
  for (int chunk = 0; chunk < 3; chunk++) {
    if (chunk) __syncthreads();
    // ---- B-stage: 128 rows x 128 bf16, 16B per thread-iter ----
    for (int i = t; i < 2048; i += 256) {
      int row = i >> 4, seg = i & 15;
      *(int4*)&bL[row*136 + seg*8] =
          *(const int4*)(Wt + (size_t)(chunk*128 + row)*128 + seg*8);
    }
    __syncthreads();
    float4v acc[4][4];
#pragma unroll
    for (int a = 0; a < 4; a++)
#pragma unroll
      for (int b = 0; b < 4; b++)
        acc[a][b] = (float4v){0.f, 0.f, 0.f, 0.f};
#pragma unroll
    for (int kk = 0; kk < 4; kk++) {
      int ko = kk*32 + q*8;
      short8 af[4], bf[4];
#pragma unroll
      for (int mf = 0; mf < 4; mf++)
        af[mf] = *(const short8*)&aL[(wr + mf*16 + ln)*136 + ko];
#pragma unroll
      for (int nf = 0; nf < 4; nf++)
        bf[nf] = *(const short8*)&bL[(wc + nf*16 + ln)*136 + ko];
#pragma unroll
      for (int mf = 0; mf < 4; mf++)
#pragma unroll
        for (int nf = 0; nf < 4; nf++)
          acc[mf][nf] = __builtin_amdgcn_mfma_f32_16x16x32_bf16(
              af[mf], bf[nf], acc[mf][nf], 0, 0, 0);
    }
    // ---- epilogue: C/D layout col=lane&15, row=q*4+reg ----
#pragma unroll
    for (int mf = 0; mf < 4; mf++)
#pragma unroll
      for (int nf = 0; nf < 4; nf++) {
        int row = wr + mf*16 + q*4;
        int col = wc + nf*16 + ln + chunk*128;
        float b4 = bias[col];
#pragma unroll
        for (int j = 0; j < 4; j++) {
          float vv = acc[mf][nf][j] + b4;
          if (do_gelu) vv = 0.5f * vv * (1.f + erff(vv * 0.70710678118654752f));
          out[(base + row + j)*NQKV + col] = vv;
        }
      }
  }
}

// ---------------------------------------------------------------------------
// K7: xh += in @ wo + wo_b  (K=128, N=128) via MFMA
// ---------------------------------------------------------------------------
__global__ __launch_bounds__(256, 2) void k_wo_mfma(
    const float* __restrict__ in, const unsigned short* __restrict__ Wt,
    const float* __restrict__ bias, float* __restrict__ xh) {
  __shared__ __align__(16) unsigned short aL[128*136];
  __shared__ __align__(16) unsigned short bL[128*136];
  size_t base = (size_t)blockIdx.x * 128;
  int t = threadIdx.x;
  { // A-stage: convert to bf16
    int r = t >> 1, half = t & 1;
    const float4* src = (const float4*)(in + (base + r)*CH + half*64);
    union { unsigned short us[8]; int4 v4; } pk;
#pragma unroll
    for (int c8 = 0; c8 < 8; c8++) {
      float4 f0 = src[c8*2], f1 = src[c8*2 + 1];
      pk.us[0] = f2bf(f0.x); pk.us[1] = f2bf(f0.y);
      pk.us[2] = f2bf(f0.z); pk.us[3] = f2bf(f0.w);
      pk.us[4] = f2bf(f1.x); pk.us[5] = f2bf(f1.y);
      pk.us[6] = f2bf(f1.z); pk.us[7] = f2bf(f1.w);
      *(int4*)&aL[r*136 + half*64 + c8*8] = pk.v4;
    }
  }
  for (int i = t; i < 2048; i += 256) {
    int row = i >> 4, seg = i & 15;
    *(int4*)&bL[row*136 + seg*8] = *(const int4*)(Wt + (size_t)row*128 + seg*8);
  }
  __syncthreads();
  int wid = t >> 6, lane = t & 63;
  int ln = lane & 15, q = lane >> 4;
  int wr = (wid >> 1)*64, wc = (wid & 1)*64;
  float4v acc[4][4];
#pragma unroll
  for (int a = 0; a < 4; a++)
#pragma unroll
    for (int b = 0; b < 4; b++)
      acc[a][b] = (float4v){0.f, 0.f, 0.f, 0.f};
#pragma unroll
  for (int kk = 0; kk < 4; kk++) {
    int ko = kk*32 + q*8;
    short8 af[4], bf[4];
#pragma unroll
    for (int mf = 0; mf < 4; mf++)
      af[mf] = *(const short8*)&aL[(wr + mf*16 + ln)*136 + ko];
#pragma unroll
    for (int nf = 0; nf < 4; nf++)
      bf[nf] = *(const short8*)&bL[(wc + nf*16 + ln)*136 + ko];
#pragma unroll
    for (int mf = 0; mf < 4; mf++)
#pragma unroll
      for (int nf = 0; nf < 4; nf++)
        acc[mf][nf] = __builtin_amdgcn_mfma_f32_16x16x32_bf16(
            af[mf], bf[nf], acc[mf][nf], 0, 0, 0);
  }
#pragma unroll
  for (int mf = 0; mf < 4; mf++)
#pragma unroll
    for (int nf = 0; nf < 4; nf++) {
      int row = wr + mf*16 + q*4;
      int col = wc + nf*16 + ln;
      float b4 = bias[col];
#pragma unroll
      for (int j = 0; j < 4; j++) {
        float* p = &xh[(base + row + j)*CH + col];
        *p += acc[mf][nf][j] + b4;
      }
    }
}

// ---------------------------------------------------------------------------
// K9: out(NCHW) = xh + hid @ mlp_w2 + mlp_b2  (K=384 in 3 chunks, N=128)
// ---------------------------------------------------------------------------
__global__ __launch_bounds__(256, 2) void k_mlp2_mfma(
    const float* __restrict__ hid, const unsigned short* __restrict__ Wt,
    const float* __restrict__ bias, const float* __restrict__ xh,
    float* __restrict__ out) {
  __shared__ __align__(16) unsigned short aL[128*136];
  __shared__ __align__(16) unsigned short bL[128*136];
  size_t base = (size_t)blockIdx.x * 128;
  int t = threadIdx.x;
  int wid = t >> 6, lane = t & 63;
  int ln = lane & 15, q = lane >> 4;
  int wr = (wid >> 1)*64, wc = (wid & 1)*64;
  float4v acc[4][4];
#pragma unroll
  for (int a = 0; a < 4; a++)
#pragma unroll
    for (int b = 0; b < 4; b++)
      acc[a][b] = (float4v){0.f, 0.f, 0.f, 0.f};
  for (int kc = 0; kc < 3; kc++) {
    if (kc) __syncthreads();
    { // A-stage chunk
      int r = t >> 1, half = t & 1;
      const float4* src = (const float4*)(hid + (base + r)*NQKV + kc*128 + half*64);
      union { unsigned short us[8]; int4 v4; } pk;
#pragma unroll
      for (int c8 = 0; c8 < 8; c8++) {
        float4 f0 = src[c8*2], f1 = src[c8*2 + 1];
        pk.us[0] = f2bf(f0.x); pk.us[1] = f2bf(f0.y);
        pk.us[2] = f2bf(f0.z); pk.us[3] = f2bf(f0.w);
        pk.us[4] = f2bf(f1.x); pk.us[5] = f2bf(f1.y);
        pk.us[6] = f2bf(f1.z); pk.us[7] = f2bf(f1.w);
        *(int4*)&aL[r*136 + half*64 + c8*8] = pk.v4;
      }
    }
    for (int i = t; i < 2048; i += 256) {
      int row = i >> 4, seg = i & 15;
      *(int4*)&bL[row*136 + seg*8] =
          *(const int4*)(Wt + (size_t)row*NQKV + kc*128 + seg*8);
    }
    __syncthreads();
#pragma unroll
    for (int kk = 0; kk < 4; kk++) {
      int ko = kk*32 + q*8;
      short8 af[4], bf[4];
#pragma unroll
      for (int mf = 0; mf < 4; mf++)
        af[mf] = *(const short8*)&aL[(wr + mf*16 + ln)*136 + ko];
#pragma unroll
      for (int nf = 0; nf < 4; nf++)
        bf[nf] = *(const short8*)&bL[(wc + nf*16 + ln)*136 + ko];
#pragma unroll
      for (int mf = 0; mf < 4; mf++)
#pragma unroll
        for (int nf = 0; nf < 4; nf++)
          acc[mf][nf] = __builtin_amdgcn_mfma_f32_16x16x32_bf16(
              af[mf], bf[nf], acc[mf][nf], 0, 0, 0);
    }
  }
#pragma unroll
  for (int mf = 0; mf < 4; mf++)
#pragma unroll
    for (int nf = 0; nf < 4; nf++) {
      int row = wr + mf*16 + q*4;
      int col = wc + nf*16 + ln;
      float b4 = bias[col];
#pragma unroll
      for (int j = 0; j < 4; j++) {
        size_t pixel = base + row + j;
        int b = (int)(pixel / (HGT*WID));
        int sp = (int)(pixel % (HGT*WID));
        out[((size_t)b*CH + col)*(HGT*WID) + sp] =
            acc[mf][nf][j] + b4 + xh[pixel*CH + col];
      }
    }
}

// ---------------------------------------------------------------------------
// K3: window means of q (cols 0..127) and k (cols 128..255)
// ---------------------------------------------------------------------------
__global__ __launch_bounds__(256) void k_winmean(const float* __restrict__ qkv,
    float* __restrict__ qwin, float* __restrict__ kwin) {
  int bp = blockIdx.x; int b = bp / P2, p = bp % P2;
  int wy = p / NWIN, wx = p % NWIN;
  int c = threadIdx.x;
  float s = 0.f;
  for (int pix = 0; pix < 64; pix++) {
    int ir = pix >> 3, iw = pix & 7;
    int hg = wy*8 + ir, wg = wx*8 + iw;
    s += qkv[(((size_t)b*HGT + hg)*WID + wg)*NQKV + c];
  }
  s *= (1.f/64.f);
  if (c < 128) qwin[(size_t)bp*128 + c] = s;
  else         kwin[(size_t)bp*128 + (c - 128)] = s;
}

// ---------------------------------------------------------------------------
// K4: routing logits (49x49 per image) + top-4
// ---------------------------------------------------------------------------
__global__ __launch_bounds__(64) void k_topk(const float* __restrict__ qwin,
    const float* __restrict__ kwin, int* __restrict__ idx) {
  int b = blockIdx.x;
  int p = threadIdx.x;
  float logits[P2];
#pragma unroll
  for (int q = 0; q < P2; q++) logits[q] = 0.f;
  const float* qp = qwin + ((size_t)b*P2 + (p < P2 ? p : 0))*128;
  const float* kp = kwin + (size_t)b*P2*128;
  for (int cc = 0; cc < 32; cc++) {
    float4 qv = ((const float4*)qp)[cc];
#pragma unroll
    for (int q = 0; q < P2; q++) {
      float4 kv = ((const float4*)(kp + q*128))[cc];
      logits[q] += qv.x*kv.x + qv.y*kv.y + qv.z*kv.z + qv.w*kv.w;
    }
  }
  if (p < P2) {
    unsigned long long used = 0ULL;
    for (int t = 0; t < TOPK; t++) {
      float best = -1e30f; int bi = 0;
#pragma unroll
      for (int q = 0; q < P2; q++) {
        bool ok = !((used >> q) & 1ULL);
        if (ok && logits[q] > best) { best = logits[q]; bi = q; }
      }
      used |= 1ULL << bi;
      idx[((size_t)b*P2 + p)*TOPK + t] = bi;
    }
  }
}

// ---------------------------------------------------------------------------
// K5: gathered window attention (fp32, online softmax) — unchanged
// ---------------------------------------------------------------------------
__global__ __launch_bounds__(256) void k_attn(const float* __restrict__ qkv,
    const int* __restrict__ idx, float* __restrict__ o) {
  __shared__ float kld[64*128];
  __shared__ float vld[64*128];
  int bp = blockIdx.x; int b = bp / P2, p = bp % P2;
  int wy = p / NWIN, wx = p % NWIN;
  int head = threadIdx.x >> 6, lane = threadIdx.x & 63;
  int ir = lane >> 3, iw = lane & 7;
  size_t pixoff = (((size_t)b*HGT + wy*8 + ir)*WID + wx*8 + iw)*NQKV;
  float qreg[32];
  {
    const float4* qp = (const float4*)(qkv + pixoff + head*32);
#pragma unroll
    for (int i = 0; i < 8; i++) {
      float4 v = qp[i];
      qreg[4*i] = v.x; qreg[4*i+1] = v.y; qreg[4*i+2] = v.z; qreg[4*i+3] = v.w;
    }
  }
  float m = -1e30f, l = 0.f;
  float oacc[32];
#pragma unroll
  for (int i = 0; i < 32; i++) oacc[i] = 0.f;

  for (int r = 0; r < TOPK; r++) {
    int win = idx[(size_t)bp*TOPK + r];
    int sy = win / NWIN, sx = win % NWIN;
    __syncthreads();
    for (int i = threadIdx.x; i < 64*32; i += 256) {
      int key = i >> 5, cq = i & 31;
      int kr = key >> 3, kw = key & 7;
      size_t po = (((size_t)b*HGT + sy*8 + kr)*WID + sx*8 + kw)*NQKV;
      ((float4*)kld)[i] = ((const float4*)(qkv + po + 128))[cq];
      ((float4*)vld)[i] = ((const float4*)(qkv + po + 256))[cq];
    }
    __syncthreads();
    for (int kc = 0; kc < 64; kc += 8) {
      float s[8];
#pragma unroll
      for (int j = 0; j < 8; j++) {
        const float4* kp = (const float4*)&kld[(kc+j)*128 + head*32];
        float acc = 0.f;
#pragma unroll
        for (int dq = 0; dq < 8; dq++) {
          float4 kv = kp[dq];
          acc += qreg[4*dq]*kv.x + qreg[4*dq+1]*kv.y + qreg[4*dq+2]*kv.z + qreg[4*dq+3]*kv.w;
        }
        s[j] = acc * ATT_SCALE;
      }
      float mc = s[0];
#pragma unroll
      for (int j = 1; j < 8; j++) mc = fmaxf(mc, s[j]);
      float mn = fmaxf(m, mc);
      float corr = __expf(m - mn);
      l *= corr;
#pragma unroll
      for (int i = 0; i < 32; i++) oacc[i] *= corr;
      m = mn;
#pragma unroll
      for (int j = 0; j < 8; j++) {
        float pex = __expf(s[j] - m);
        l += pex;
        const float4* vp = (const float4*)&vld[(kc+j)*128 + head*32];
#pragma unroll
        for (int dq = 0; dq < 8; dq++) {
          float4 vv = vp[dq];
          oacc[4*dq]   += pex*vv.x; oacc[4*dq+1] += pex*vv.y;
          oacc[4*dq+2] += pex*vv.z; oacc[4*dq+3] += pex*vv.w;
        }
      }
    }
  }
  float inv = 1.f / l;
  float* op = o + (pixoff / NQKV)*CH + head*32;
#pragma unroll
  for (int q = 0; q < 8; q++)
    ((float4*)op)[q] = make_float4(oacc[q*4]*inv, oacc[q*4+1]*inv,
                                   oacc[q*4+2]*inv, oacc[q*4+3]*inv);
}

// ---------------------------------------------------------------------------
// K6: o += dwconv5x5(v) + lepe_b
// ---------------------------------------------------------------------------
__global__ __launch_bounds__(256) void k_lepe(const float* __restrict__ qkv,
    const float* __restrict__ lw, const float* __restrict__ lb,
    float* __restrict__ o) {
  int h = blockIdx.x, b = blockIdx.y;
  int c = threadIdx.x & 127, wi = threadIdx.x >> 7;
  float w[25];
#pragma unroll
  for (int i = 0; i < 25; i++) w[i] = lw[c*25 + i];
  float bias = lb[c];
  for (int w0 = wi; w0 < WID; w0 += 2) {
    float s = bias;
#pragma unroll
    for (int dy = 0; dy < 5; dy++) {
      int hy = h + dy - 2; if ((unsigned)hy >= HGT) continue;
#pragma unroll
      for (int dx = 0; dx < 5; dx++) {
        int wx = w0 + dx - 2; if ((unsigned)wx >= WID) continue;
        s += qkv[(((size_t)b*HGT + hy)*WID + wx)*NQKV + 256 + c] * w[dy*5 + dx];
      }
    }
    size_t oi = (((size_t)b*HGT + h)*WID + w0)*CH + c;
    o[oi] += s;
  }
}

// ---------------------------------------------------------------------------
extern "C" void kernel_launch(void* const* d_in, const int* in_sizes, int n_in,
                              void* d_out, int out_size, void* d_ws, size_t ws_size,
                              hipStream_t stream) {
  const float* x      = (const float*)d_in[0];
  const float* pos_w  = (const float*)d_in[1];
  const float* pos_b  = (const float*)d_in[2];
  const float* ln1_g  = (const float*)d_in[3];
  const float* ln1_b  = (const float*)d_in[4];
  const float* qkv_w  = (const float*)d_in[5];
  const float* qkv_b  = (const float*)d_in[6];
  const float* lepe_w = (const float*)d_in[7];
  const float* lepe_b = (const float*)d_in[8];
  const float* wo_w   = (const float*)d_in[9];
  const float* wo_b   = (const float*)d_in[10];
  const float* ln2_g  = (const float*)d_in[11];
  const float* ln2_b  = (const float*)d_in[12];
  const float* mlp_w1 = (const float*)d_in[13];
  const float* mlp_b1 = (const float*)d_in[14];
  const float* mlp_w2 = (const float*)d_in[15];
  const float* mlp_b2 = (const float*)d_in[16];

  float* ws   = (float*)d_ws;
  float* xh   = ws;                          // NPIX*128
  float* qkv  = xh  + (size_t)NPIX*CH;       // NPIX*384
  float* o    = qkv + (size_t)NPIX*NQKV;     // NPIX*128
  float* qwin = o   + (size_t)NPIX*CH;       // B*49*128
  float* kwin = qwin + (size_t)BATCH*P2*128; // B*49*128
  int*   idx  = (int*)(kwin + (size_t)BATCH*P2*128); // B*49*4
  unsigned short* Wq = (unsigned short*)(idx + BATCH*P2*TOPK); // 384*128
  unsigned short* Wo = Wq + 384*128;         // 128*128
  unsigned short* W1 = Wo + 128*128;         // 384*128
  unsigned short* W2 = W1 + 384*128;         // 128*384
  float* hid  = qkv;                         // reuse qkv buffer for MLP hidden

  k_prep<<<1024, 128, 0, stream>>>(qkv_w, wo_w, mlp_w1, mlp_w2, Wq, Wo, W1, W2);
  k_posconv<<<dim3(CH, BATCH), 256, 0, stream>>>(x, pos_w, pos_b, xh);
  k_ln_gemm_mfma<<<NPIX/128, 256, 0, stream>>>(xh, ln1_g, ln1_b, Wq, qkv_b, qkv, 0);
  k_winmean<<<BATCH*P2, 256, 0, stream>>>(qkv, qwin, kwin);
  k_topk<<<BATCH, 64, 0, stream>>>(qwin, kwin, idx);
  k_attn<<<BATCH*P2, 256, 0, stream>>>(qkv, idx, o);
  k_lepe<<<dim3(HGT, BATCH), 256, 0, stream>>>(qkv, lepe_w, lepe_b, o);
  k_wo_mfma<<<NPIX/128, 256, 0, stream>>>(o, Wo, wo_b, xh);
  k_ln_gemm_mfma<<<NPIX/128, 256, 0, stream>>>(xh, ln2_g, ln2_b, W1, mlp_b1, hid, 1);
  k_mlp2_mfma<<<NPIX/128, 256, 0, stream>>>(hid, W2, mlp_b2, xh, (float*)d_out);
}

// Round 3
// 825.115 us; speedup vs baseline: 1.7384x; 1.0351x over previous
//
#include <hip/hip_runtime.h>
#include <math.h>

#define BATCH 16
#define CH    128
#define HGT   56
#define WID   56
#define NPIX  (BATCH*HGT*WID)   // 50176
#define NQKV  384
#define NWIN  7
#define P2    49
#define TOPK  4
#define ATT_SCALE 0.088388347648318447f   // 128^-0.5

typedef __attribute__((ext_vector_type(8))) short short8;
typedef __attribute__((ext_vector_type(4))) float float4v;

static __device__ __forceinline__ unsigned short f2bf(float f) {
  unsigned u = __float_as_uint(f);
  u += 0x7fffu + ((u >> 16) & 1u);   // round-to-nearest-even
  return (unsigned short)(u >> 16);
}

static __device__ __forceinline__ short8 cvt8(float4 a, float4 b) {
  union { unsigned short us[8]; short8 s8; } u;
  u.us[0] = f2bf(a.x); u.us[1] = f2bf(a.y); u.us[2] = f2bf(a.z); u.us[3] = f2bf(a.w);
  u.us[4] = f2bf(b.x); u.us[5] = f2bf(b.y); u.us[6] = f2bf(b.z); u.us[7] = f2bf(b.w);
  return u.s8;
}

// ---------------------------------------------------------------------------
// K0: weight prep — convert to bf16 and transpose to [N][K] layout.
// ---------------------------------------------------------------------------
__global__ __launch_bounds__(128) void k_prep(
    const float* __restrict__ qkv_w, const float* __restrict__ wo_w,
    const float* __restrict__ mlp_w1, const float* __restrict__ mlp_w2,
    unsigned short* __restrict__ Wq, unsigned short* __restrict__ Wo,
    unsigned short* __restrict__ W1, unsigned short* __restrict__ W2) {
  int bx = blockIdx.x, t = threadIdx.x;
  if (bx < 384) {
    int n = bx;
    Wq[n*128 + t] = f2bf(qkv_w[(size_t)t*384 + n]);
  } else if (bx < 512) {
    int n = bx - 384;
    Wo[n*128 + t] = f2bf(wo_w[(size_t)t*128 + n]);
  } else if (bx < 896) {
    int n = bx - 512;
    W1[n*128 + t] = f2bf(mlp_w1[(size_t)t*384 + n]);
  } else {
    int n = bx - 896;
    for (int k = t; k < 384; k += 128)
      W2[n*384 + k] = f2bf(mlp_w2[(size_t)k*128 + n]);
  }
}

// ---------------------------------------------------------------------------
// K1: x(NCHW) -> xh(NHWC) = x + dwconv3x3(x)
// ---------------------------------------------------------------------------
__global__ __launch_bounds__(256) void k_posconv(const float* __restrict__ x,
    const float* __restrict__ pw, const float* __restrict__ pb,
    float* __restrict__ xh) {
  int c = blockIdx.x, b = blockIdx.y;
  const float* xp = x + ((size_t)(b*CH + c))*(HGT*WID);
  float w[9];
#pragma unroll
  for (int i = 0; i < 9; i++) w[i] = pw[c*9 + i];
  float bias = pb[c];
  float* xhb = xh + (size_t)b*HGT*WID*CH + c;
  for (int pix = threadIdx.x; pix < HGT*WID; pix += 256) {
    int h = pix / WID, wv = pix - h*WID;
    float s = bias + xp[pix];
#pragma unroll
    for (int dy = 0; dy < 3; dy++) {
      int hy = h + dy - 1; if ((unsigned)hy >= HGT) continue;
#pragma unroll
      for (int dx = 0; dx < 3; dx++) {
        int wx = wv + dx - 1; if ((unsigned)wx >= WID) continue;
        s += xp[hy*WID + wx] * w[dy*3 + dx];
      }
    }
    xhb[(size_t)pix*CH] = s;
  }
}

// ---------------------------------------------------------------------------
// K2/K8: fused LN + MFMA GEMM. M-tile 128, N=384 (3 chunks of 128), K=128.
// ---------------------------------------------------------------------------
__global__ __launch_bounds__(256, 2) void k_ln_gemm_mfma(
    const float* __restrict__ in, const float* __restrict__ g,
    const float* __restrict__ be, const unsigned short* __restrict__ Wt,
    const float* __restrict__ bias, float* __restrict__ out, int do_gelu) {
  __shared__ __align__(16) unsigned short aL[128*136];
  __shared__ __align__(16) unsigned short bL[128*136];
  size_t base = (size_t)blockIdx.x * 128;
  int t = threadIdx.x;
  { // ---- LN + A-stage: threads 2r, 2r+1 handle row r halves ----
    int r = t >> 1, half = t & 1;
    const float4* src = (const float4*)(in + (base + r)*CH + half*64);
    float v[64];
    float s = 0.f, ss = 0.f;
#pragma unroll
    for (int i = 0; i < 16; i++) {
      float4 f = src[i];
      v[4*i] = f.x; v[4*i+1] = f.y; v[4*i+2] = f.z; v[4*i+3] = f.w;
      s += f.x + f.y + f.z + f.w;
      ss += f.x*f.x + f.y*f.y + f.z*f.z + f.w*f.w;
    }
    s += __shfl_xor(s, 1); ss += __shfl_xor(ss, 1);
    float m  = s * (1.f/128.f);
    float var = ss * (1.f/128.f) - m*m;
    float rs = rsqrtf(var + 1e-6f);
    union { unsigned short us[8]; int4 v4; } pk;
#pragma unroll
    for (int c8 = 0; c8 < 8; c8++) {
#pragma unroll
      for (int j = 0; j < 8; j++) {
        int ch = half*64 + c8*8 + j;
        pk.us[j] = f2bf((v[c8*8 + j] - m) * rs * g[ch] + be[ch]);
      }
      *(int4*)&aL[r*136 + half*64 + c8*8] = pk.v4;
    }
  }
  int wid = t >> 6, lane = t & 63;
  int ln = lane & 15, q = lane >> 4;
  int wr = (wid >> 1)*64, wc = (wid & 1)*64;
  for (int chunk = 0; chunk < 3; chunk++) {
    if (chunk) __syncthreads();
    for (int i = t; i < 2048; i += 256) {
      int row = i >> 4, seg = i & 15;
      *(int4*)&bL[row*136 + seg*8] =
          *(const int4*)(Wt + (size_t)(chunk*128 + row)*128 + seg*8);
    }
    __syncthreads();
    float4v acc[4][4];
#pragma unroll
    for (int a = 0; a < 4; a++)
#pragma unroll
      for (int b = 0; b < 4; b++)
        acc[a][b] = (float4v){0.f, 0.f, 0.f, 0.f};
#pragma unroll
    for (int kk = 0; kk < 4; kk++) {
      int ko = kk*32 + q*8;
      short8 af[4], bf[4];
#pragma unroll
      for (int mf = 0; mf < 4; mf++)
        af[mf] = *(const short8*)&aL[(wr + mf*16 + ln)*136 + ko];
#pragma unroll
      for (int nf = 0; nf < 4; nf++)
        bf[nf] = *(const short8*)&bL[(wc + nf*16 + ln)*136 + ko];
#pragma unroll
      for (int mf = 0; mf < 4; mf++)
#pragma unroll
        for (int nf = 0; nf < 4; nf++)
          acc[mf][nf] = __builtin_amdgcn_mfma_f32_16x16x32_bf16(
              af[mf], bf[nf], acc[mf][nf], 0, 0, 0);
    }
#pragma unroll
    for (int mf = 0; mf < 4; mf++)
#pragma unroll
      for (int nf = 0; nf < 4; nf++) {
        int row = wr + mf*16 + q*4;
        int col = wc + nf*16 + ln + chunk*128;
        float b4 = bias[col];
#pragma unroll
        for (int j = 0; j < 4; j++) {
          float vv = acc[mf][nf][j] + b4;
          if (do_gelu) vv = 0.5f * vv * (1.f + erff(vv * 0.70710678118654752f));
          out[(base + row + j)*NQKV + col] = vv;
        }
      }
  }
}

// ---------------------------------------------------------------------------
// K_vt: vT[b][c][hw] bf16  <- qkv cols [256,384) (LDS-tiled transpose)
// grid NPIX/32 blocks x 256 threads
// ---------------------------------------------------------------------------
__global__ __launch_bounds__(256) void k_vt(const float* __restrict__ qkv,
    unsigned short* __restrict__ vT) {
  __shared__ unsigned short tile[128*40];
  int pg0 = blockIdx.x * 32;
  int b = pg0 / (HGT*WID), sp0 = pg0 % (HGT*WID);
  int t = threadIdx.x;
  {
    int pl = t >> 3, cg = t & 7;          // pixel-local, channel-group
    const float4* src = (const float4*)(qkv + (size_t)(pg0 + pl)*NQKV + 256 + cg*16);
#pragma unroll
    for (int i = 0; i < 4; i++) {
      float4 f = src[i];
      int c = cg*16 + i*4;
      tile[(c+0)*40 + pl] = f2bf(f.x);
      tile[(c+1)*40 + pl] = f2bf(f.y);
      tile[(c+2)*40 + pl] = f2bf(f.z);
      tile[(c+3)*40 + pl] = f2bf(f.w);
    }
  }
  __syncthreads();
  int c = t >> 1, half = t & 1;
  unsigned short* dst = vT + ((size_t)b*CH + c)*(HGT*WID) + sp0 + half*16;
  const int4* srcl = (const int4*)&tile[c*40 + half*16];
  ((int4*)dst)[0] = srcl[0];
  ((int4*)dst)[1] = srcl[1];
}

// ---------------------------------------------------------------------------
// K3: window means of q (cols 0..127) and k (cols 128..255)  (fp32 — routing)
// ---------------------------------------------------------------------------
__global__ __launch_bounds__(256) void k_winmean(const float* __restrict__ qkv,
    float* __restrict__ qwin, float* __restrict__ kwin) {
  int bp = blockIdx.x; int b = bp / P2, p = bp % P2;
  int wy = p / NWIN, wx = p % NWIN;
  int c = threadIdx.x;
  float s = 0.f;
  for (int pix = 0; pix < 64; pix++) {
    int ir = pix >> 3, iw = pix & 7;
    int hg = wy*8 + ir, wg = wx*8 + iw;
    s += qkv[(((size_t)b*HGT + hg)*WID + wg)*NQKV + c];
  }
  s *= (1.f/64.f);
  if (c < 128) qwin[(size_t)bp*128 + c] = s;
  else         kwin[(size_t)bp*128 + (c - 128)] = s;
}

// ---------------------------------------------------------------------------
// K4: routing logits (49x49 per image) + top-4
// ---------------------------------------------------------------------------
__global__ __launch_bounds__(64) void k_topk(const float* __restrict__ qwin,
    const float* __restrict__ kwin, int* __restrict__ idx) {
  int b = blockIdx.x;
  int p = threadIdx.x;
  float logits[P2];
#pragma unroll
  for (int q = 0; q < P2; q++) logits[q] = 0.f;
  const float* qp = qwin + ((size_t)b*P2 + (p < P2 ? p : 0))*128;
  const float* kp = kwin + (size_t)b*P2*128;
  for (int cc = 0; cc < 32; cc++) {
    float4 qv = ((const float4*)qp)[cc];
#pragma unroll
    for (int q = 0; q < P2; q++) {
      float4 kv = ((const float4*)(kp + q*128))[cc];
      logits[q] += qv.x*kv.x + qv.y*kv.y + qv.z*kv.z + qv.w*kv.w;
    }
  }
  if (p < P2) {
    unsigned long long used = 0ULL;
    for (int t = 0; t < TOPK; t++) {
      float best = -1e30f; int bi = 0;
#pragma unroll
      for (int q = 0; q < P2; q++) {
        bool ok = !((used >> q) & 1ULL);
        if (ok && logits[q] > best) { best = logits[q]; bi = q; }
      }
      used |= 1ULL << bi;
      idx[((size_t)b*P2 + p)*TOPK + t] = bi;
    }
  }
}

// ---------------------------------------------------------------------------
// K5: MFMA attention. block = one (b,p) query window, wave = head.
// S = Q@K^T via mfma (K B-frags straight from fp32 qkv, cvt in reg);
// online softmax per C-row (shfl over 16-lane groups); P -> per-wave
// XOR-swizzled LDS -> A-frags; PV with V from bf16 vT (16B global B-frags).
// ---------------------------------------------------------------------------
#define PLS 72
__global__ __launch_bounds__(256) void k_attn_mfma(
    const float* __restrict__ qkv, const unsigned short* __restrict__ vT,
    const int* __restrict__ idx, float* __restrict__ o) {
  __shared__ unsigned short pL[4][64*PLS];
  int bp = blockIdx.x; int b = bp / P2, p = bp % P2;
  int wy = p / NWIN, wx = p % NWIN;
  int h = threadIdx.x >> 6, lane = threadIdx.x & 63;
  int ln = lane & 15, q = lane >> 4;

  // Q A-frags (pre-scaled by ATT_SCALE)
  short8 aq[4];
#pragma unroll
  for (int mf = 0; mf < 4; mf++) {
    int pq = mf*16 + ln;
    const float* qp = qkv + (((size_t)b*HGT + wy*8 + (pq>>3))*WID + wx*8 + (pq&7))*NQKV + h*32 + q*8;
    float4 f0 = *(const float4*)qp, f1 = *(const float4*)(qp + 4);
    f0.x *= ATT_SCALE; f0.y *= ATT_SCALE; f0.z *= ATT_SCALE; f0.w *= ATT_SCALE;
    f1.x *= ATT_SCALE; f1.y *= ATT_SCALE; f1.z *= ATT_SCALE; f1.w *= ATT_SCALE;
    aq[mf] = cvt8(f0, f1);
  }

  float m_run[4][4], l_run[4][4];
  float4v facc[4][2];
#pragma unroll
  for (int mf = 0; mf < 4; mf++) {
#pragma unroll
    for (int j = 0; j < 4; j++) { m_run[mf][j] = -1e30f; l_run[mf][j] = 0.f; }
    facc[mf][0] = (float4v){0.f,0.f,0.f,0.f};
    facc[mf][1] = (float4v){0.f,0.f,0.f,0.f};
  }

  unsigned short* myP = &pL[h][0];
  int swr = ((ln >> 2) & 3) * 16;     // read-side swizzle (fn of A-row)

  for (int r = 0; r < TOPK; r++) {
    int win = idx[(size_t)bp*TOPK + r];
    int sy = win / NWIN, sx = win % NWIN;
    // K B-frags
    short8 bk[4];
#pragma unroll
    for (int nf = 0; nf < 4; nf++) {
      int kp = nf*16 + ln;
      const float* kpp = qkv + (((size_t)b*HGT + sy*8 + (kp>>3))*WID + sx*8 + (kp&7))*NQKV + 128 + h*32 + q*8;
      bk[nf] = cvt8(*(const float4*)kpp, *(const float4*)(kpp + 4));
    }
    // S = Q K^T
    float4v sacc[4][4];
#pragma unroll
    for (int mf = 0; mf < 4; mf++)
#pragma unroll
      for (int nf = 0; nf < 4; nf++)
        sacc[mf][nf] = (float4v){0.f,0.f,0.f,0.f};
#pragma unroll
    for (int mf = 0; mf < 4; mf++)
#pragma unroll
      for (int nf = 0; nf < 4; nf++)
        sacc[mf][nf] = __builtin_amdgcn_mfma_f32_16x16x32_bf16(
            aq[mf], bk[nf], sacc[mf][nf], 0, 0, 0);
    // online softmax per row; write P (bf16) to swizzled LDS
#pragma unroll
    for (int mf = 0; mf < 4; mf++) {
#pragma unroll
      for (int j = 0; j < 4; j++) {
        float s0 = sacc[mf][0][j], s1 = sacc[mf][1][j];
        float s2 = sacc[mf][2][j], s3 = sacc[mf][3][j];
        float mx = fmaxf(fmaxf(s0, s1), fmaxf(s2, s3));
        mx = fmaxf(mx, __shfl_xor(mx, 1));
        mx = fmaxf(mx, __shfl_xor(mx, 2));
        mx = fmaxf(mx, __shfl_xor(mx, 4));
        mx = fmaxf(mx, __shfl_xor(mx, 8));
        float mo = m_run[mf][j];
        float mn = fmaxf(mo, mx);
        float corr = __expf(mo - mn);
        m_run[mf][j] = mn;
        float e0 = __expf(s0 - mn), e1 = __expf(s1 - mn);
        float e2 = __expf(s2 - mn), e3 = __expf(s3 - mn);
        float ls = e0 + e1 + e2 + e3;
        ls += __shfl_xor(ls, 1);
        ls += __shfl_xor(ls, 2);
        ls += __shfl_xor(ls, 4);
        ls += __shfl_xor(ls, 8);
        l_run[mf][j] = l_run[mf][j]*corr + ls;
        facc[mf][0][j] *= corr; facc[mf][1][j] *= corr;
        int rowoff = (mf*16 + q*4 + j)*PLS;
        int sww = q*16;   // write-side swizzle (fn of P-row)
        myP[rowoff + (( 0 + ln) ^ sww)] = f2bf(e0);
        myP[rowoff + ((16 + ln) ^ sww)] = f2bf(e1);
        myP[rowoff + ((32 + ln) ^ sww)] = f2bf(e2);
        myP[rowoff + ((48 + ln) ^ sww)] = f2bf(e3);
      }
    }
    // PV (wave-local LDS; wave-synchronous, no barrier needed)
#pragma unroll
    for (int kk = 0; kk < 2; kk++) {
      short8 ap[4];
#pragma unroll
      for (int mf = 0; mf < 4; mf++)
        ap[mf] = *(const short8*)&myP[(mf*16 + ln)*PLS + ((kk*32 + q*8) ^ swr)];
      short8 bv[2];
#pragma unroll
      for (int nf2 = 0; nf2 < 2; nf2++) {
        int d = h*32 + nf2*16 + ln;
        int K0 = kk*32 + q*8;
        const unsigned short* vp = vT + ((size_t)b*CH + d)*(HGT*WID)
            + (sy*8 + (K0 >> 3))*WID + sx*8;
        bv[nf2] = *(const short8*)vp;
      }
#pragma unroll
      for (int mf = 0; mf < 4; mf++)
#pragma unroll
        for (int nf2 = 0; nf2 < 2; nf2++)
          facc[mf][nf2] = __builtin_amdgcn_mfma_f32_16x16x32_bf16(
              ap[mf], bv[nf2], facc[mf][nf2], 0, 0, 0);
    }
  }
  // epilogue
#pragma unroll
  for (int mf = 0; mf < 4; mf++)
#pragma unroll
    for (int j = 0; j < 4; j++) {
      float inv = 1.f / l_run[mf][j];
      int prow = mf*16 + q*4 + j;
      size_t pg = ((size_t)b*HGT + wy*8 + (prow>>3))*WID + wx*8 + (prow&7);
      o[pg*CH + h*32 + ln]      = facc[mf][0][j] * inv;
      o[pg*CH + h*32 + 16 + ln] = facc[mf][1][j] * inv;
    }
}

// ---------------------------------------------------------------------------
// K6: o += dwconv5x5(v) + lepe_b
// ---------------------------------------------------------------------------
__global__ __launch_bounds__(256) void k_lepe(const float* __restrict__ qkv,
    const float* __restrict__ lw, const float* __restrict__ lb,
    float* __restrict__ o) {
  int h = blockIdx.x, b = blockIdx.y;
  int c = threadIdx.x & 127, wi = threadIdx.x >> 7;
  float w[25];
#pragma unroll
  for (int i = 0; i < 25; i++) w[i] = lw[c*25 + i];
  float bias = lb[c];
  for (int w0 = wi; w0 < WID; w0 += 2) {
    float s = bias;
#pragma unroll
    for (int dy = 0; dy < 5; dy++) {
      int hy = h + dy - 2; if ((unsigned)hy >= HGT) continue;
#pragma unroll
      for (int dx = 0; dx < 5; dx++) {
        int wx = w0 + dx - 2; if ((unsigned)wx >= WID) continue;
        s += qkv[(((size_t)b*HGT + hy)*WID + wx)*NQKV + 256 + c] * w[dy*5 + dx];
      }
    }
    size_t oi = (((size_t)b*HGT + h)*WID + w0)*CH + c;
    o[oi] += s;
  }
}

// ---------------------------------------------------------------------------
// K7: xh += in @ wo + wo_b  (K=128, N=128) via MFMA
// ---------------------------------------------------------------------------
__global__ __launch_bounds__(256, 2) void k_wo_mfma(
    const float* __restrict__ in, const unsigned short* __restrict__ Wt,
    const float* __restrict__ bias, float* __restrict__ xh) {
  __shared__ __align__(16) unsigned short aL[128*136];
  __shared__ __align__(16) unsigned short bL[128*136];
  size_t base = (size_t)blockIdx.x * 128;
  int t = threadIdx.x;
  {
    int r = t >> 1, half = t & 1;
    const float4* src = (const float4*)(in + (base + r)*CH + half*64);
    union { unsigned short us[8]; int4 v4; } pk;
#pragma unroll
    for (int c8 = 0; c8 < 8; c8++) {
      float4 f0 = src[c8*2], f1 = src[c8*2 + 1];
      pk.us[0] = f2bf(f0.x); pk.us[1] = f2bf(f0.y);
      pk.us[2] = f2bf(f0.z); pk.us[3] = f2bf(f0.w);
      pk.us[4] = f2bf(f1.x); pk.us[5] = f2bf(f1.y);
      pk.us[6] = f2bf(f1.z); pk.us[7] = f2bf(f1.w);
      *(int4*)&aL[r*136 + half*64 + c8*8] = pk.v4;
    }
  }
  for (int i = t; i < 2048; i += 256) {
    int row = i >> 4, seg = i & 15;
    *(int4*)&bL[row*136 + seg*8] = *(const int4*)(Wt + (size_t)row*128 + seg*8);
  }
  __syncthreads();
  int wid = t >> 6, lane = t & 63;
  int ln = lane & 15, q = lane >> 4;
  int wr = (wid >> 1)*64, wc = (wid & 1)*64;
  float4v acc[4][4];
#pragma unroll
  for (int a = 0; a < 4; a++)
#pragma unroll
    for (int b = 0; b < 4; b++)
      acc[a][b] = (float4v){0.f, 0.f, 0.f, 0.f};
#pragma unroll
  for (int kk = 0; kk < 4; kk++) {
    int ko = kk*32 + q*8;
    short8 af[4], bf[4];
#pragma unroll
    for (int mf = 0; mf < 4; mf++)
      af[mf] = *(const short8*)&aL[(wr + mf*16 + ln)*136 + ko];
#pragma unroll
    for (int nf = 0; nf < 4; nf++)
      bf[nf] = *(const short8*)&bL[(wc + nf*16 + ln)*136 + ko];
#pragma unroll
    for (int mf = 0; mf < 4; mf++)
#pragma unroll
      for (int nf = 0; nf < 4; nf++)
        acc[mf][nf] = __builtin_amdgcn_mfma_f32_16x16x32_bf16(
            af[mf], bf[nf], acc[mf][nf], 0, 0, 0);
  }
#pragma unroll
  for (int mf = 0; mf < 4; mf++)
#pragma unroll
    for (int nf = 0; nf < 4; nf++) {
      int row = wr + mf*16 + q*4;
      int col = wc + nf*16 + ln;
      float b4 = bias[col];
#pragma unroll
      for (int j = 0; j < 4; j++) {
        float* p = &xh[(base + row + j)*CH + col];
        *p += acc[mf][nf][j] + b4;
      }
    }
}

// ---------------------------------------------------------------------------
// K9: out(NCHW) = xh + hid @ mlp_w2 + mlp_b2  (K=384 in 3 chunks, N=128)
// ---------------------------------------------------------------------------
__global__ __launch_bounds__(256, 2) void k_mlp2_mfma(
    const float* __restrict__ hid, const unsigned short* __restrict__ Wt,
    const float* __restrict__ bias, const float* __restrict__ xh,
    float* __restrict__ out) {
  __shared__ __align__(16) unsigned short aL[128*136];
  __shared__ __align__(16) unsigned short bL[128*136];
  size_t base = (size_t)blockIdx.x * 128;
  int t = threadIdx.x;
  int wid = t >> 6, lane = t & 63;
  int ln = lane & 15, q = lane >> 4;
  int wr = (wid >> 1)*64, wc = (wid & 1)*64;
  float4v acc[4][4];
#pragma unroll
  for (int a = 0; a < 4; a++)
#pragma unroll
    for (int b = 0; b < 4; b++)
      acc[a][b] = (float4v){0.f, 0.f, 0.f, 0.f};
  for (int kc = 0; kc < 3; kc++) {
    if (kc) __syncthreads();
    {
      int r = t >> 1, half = t & 1;
      const float4* src = (const float4*)(hid + (base + r)*NQKV + kc*128 + half*64);
      union { unsigned short us[8]; int4 v4; } pk;
#pragma unroll
      for (int c8 = 0; c8 < 8; c8++) {
        float4 f0 = src[c8*2], f1 = src[c8*2 + 1];
        pk.us[0] = f2bf(f0.x); pk.us[1] = f2bf(f0.y);
        pk.us[2] = f2bf(f0.z); pk.us[3] = f2bf(f0.w);
        pk.us[4] = f2bf(f1.x); pk.us[5] = f2bf(f1.y);
        pk.us[6] = f2bf(f1.z); pk.us[7] = f2bf(f1.w);
        *(int4*)&aL[r*136 + half*64 + c8*8] = pk.v4;
      }
    }
    for (int i = t; i < 2048; i += 256) {
      int row = i >> 4, seg = i & 15;
      *(int4*)&bL[row*136 + seg*8] =
          *(const int4*)(Wt + (size_t)row*NQKV + kc*128 + seg*8);
    }
    __syncthreads();
#pragma unroll
    for (int kk = 0; kk < 4; kk++) {
      int ko = kk*32 + q*8;
      short8 af[4], bf[4];
#pragma unroll
      for (int mf = 0; mf < 4; mf++)
        af[mf] = *(const short8*)&aL[(wr + mf*16 + ln)*136 + ko];
#pragma unroll
      for (int nf = 0; nf < 4; nf++)
        bf[nf] = *(const short8*)&bL[(wc + nf*16 + ln)*136 + ko];
#pragma unroll
      for (int mf = 0; mf < 4; mf++)
#pragma unroll
        for (int nf = 0; nf < 4; nf++)
          acc[mf][nf] = __builtin_amdgcn_mfma_f32_16x16x32_bf16(
              af[mf], bf[nf], acc[mf][nf], 0, 0, 0);
    }
  }
#pragma unroll
  for (int mf = 0; mf < 4; mf++)
#pragma unroll
    for (int nf = 0; nf < 4; nf++) {
      int row = wr + mf*16 + q*4;
      int col = wc + nf*16 + ln;
      float b4 = bias[col];
#pragma unroll
      for (int j = 0; j < 4; j++) {
        size_t pixel = base + row + j;
        int b = (int)(pixel / (HGT*WID));
        int sp = (int)(pixel % (HGT*WID));
        out[((size_t)b*CH + col)*(HGT*WID) + sp] =
            acc[mf][nf][j] + b4 + xh[pixel*CH + col];
      }
    }
}

// ---------------------------------------------------------------------------
extern "C" void kernel_launch(void* const* d_in, const int* in_sizes, int n_in,
                              void* d_out, int out_size, void* d_ws, size_t ws_size,
                              hipStream_t stream) {
  const float* x      = (const float*)d_in[0];
  const float* pos_w  = (const float*)d_in[1];
  const float* pos_b  = (const float*)d_in[2];
  const float* ln1_g  = (const float*)d_in[3];
  const float* ln1_b  = (const float*)d_in[4];
  const float* qkv_w  = (const float*)d_in[5];
  const float* qkv_b  = (const float*)d_in[6];
  const float* lepe_w = (const float*)d_in[7];
  const float* lepe_b = (const float*)d_in[8];
  const float* wo_w   = (const float*)d_in[9];
  const float* wo_b   = (const float*)d_in[10];
  const float* ln2_g  = (const float*)d_in[11];
  const float* ln2_b  = (const float*)d_in[12];
  const float* mlp_w1 = (const float*)d_in[13];
  const float* mlp_b1 = (const float*)d_in[14];
  const float* mlp_w2 = (const float*)d_in[15];
  const float* mlp_b2 = (const float*)d_in[16];

  float* ws   = (float*)d_ws;
  float* xh   = ws;                          // NPIX*128
  float* qkv  = xh  + (size_t)NPIX*CH;       // NPIX*384
  float* o    = qkv + (size_t)NPIX*NQKV;     // NPIX*128
  float* qwin = o   + (size_t)NPIX*CH;       // B*49*128
  float* kwin = qwin + (size_t)BATCH*P2*128; // B*49*128
  int*   idx  = (int*)(kwin + (size_t)BATCH*P2*128); // B*49*4
  unsigned short* Wq = (unsigned short*)(idx + BATCH*P2*TOPK); // 384*128
  unsigned short* Wo = Wq + 384*128;         // 128*128
  unsigned short* W1 = Wo + 128*128;         // 384*128
  unsigned short* W2 = W1 + 384*128;         // 128*384
  unsigned short* vT = W2 + 128*384;         // NPIX*128 bf16
  float* hid  = qkv;                         // reuse qkv buffer for MLP hidden

  k_prep<<<1024, 128, 0, stream>>>(qkv_w, wo_w, mlp_w1, mlp_w2, Wq, Wo, W1, W2);
  k_posconv<<<dim3(CH, BATCH), 256, 0, stream>>>(x, pos_w, pos_b, xh);
  k_ln_gemm_mfma<<<NPIX/128, 256, 0, stream>>>(xh, ln1_g, ln1_b, Wq, qkv_b, qkv, 0);
  k_vt<<<NPIX/32, 256, 0, stream>>>(qkv, vT);
  k_winmean<<<BATCH*P2, 256, 0, stream>>>(qkv, qwin, kwin);
  k_topk<<<BATCH, 64, 0, stream>>>(qwin, kwin, idx);
  k_attn_mfma<<<BATCH*P2, 256, 0, stream>>>(qkv, vT, idx, o);
  k_lepe<<<dim3(HGT, BATCH), 256, 0, stream>>>(qkv, lepe_w, lepe_b, o);
  k_wo_mfma<<<NPIX/128, 256, 0, stream>>>(o, Wo, wo_b, xh);
  k_ln_gemm_mfma<<<NPIX/128, 256, 0, stream>>>(xh, ln2_g, ln2_b, W1, mlp_b1, hid, 1);
  k_mlp2_mfma<<<NPIX/128, 256, 0, stream>>>(hid, W2, mlp_b2, xh, (float*)d_out);
}

// Round 4
// 558.422 us; speedup vs baseline: 2.5687x; 1.4776x over previous
//
#include <hip/hip_runtime.h>
#include <math.h>

#define BATCH 16
#define CH    128
#define HGT   56
#define WID   56
#define NPIX  (BATCH*HGT*WID)   // 50176
#define NQKV  384
#define NWIN  7
#define P2    49
#define TOPK  4
#define ATT_SCALE 0.088388347648318447f   // 128^-0.5

typedef __attribute__((ext_vector_type(8))) short short8;
typedef __attribute__((ext_vector_type(4))) float float4v;

static __device__ __forceinline__ unsigned short f2bf(float f) {
  unsigned u = __float_as_uint(f);
  u += 0x7fffu + ((u >> 16) & 1u);   // round-to-nearest-even
  return (unsigned short)(u >> 16);
}
static __device__ __forceinline__ float bf2f(unsigned short u) {
  return __uint_as_float((unsigned)u << 16);
}

static __device__ __forceinline__ short8 cvt8(float4 a, float4 b) {
  union { unsigned short us[8]; short8 s8; } u;
  u.us[0] = f2bf(a.x); u.us[1] = f2bf(a.y); u.us[2] = f2bf(a.z); u.us[3] = f2bf(a.w);
  u.us[4] = f2bf(b.x); u.us[5] = f2bf(b.y); u.us[6] = f2bf(b.z); u.us[7] = f2bf(b.w);
  return u.s8;
}

// ---------------------------------------------------------------------------
// K0: weight prep — convert to bf16 and transpose to [N][K] layout.
// ---------------------------------------------------------------------------
__global__ __launch_bounds__(128) void k_prep(
    const float* __restrict__ qkv_w, const float* __restrict__ wo_w,
    const float* __restrict__ mlp_w1, const float* __restrict__ mlp_w2,
    unsigned short* __restrict__ Wq, unsigned short* __restrict__ Wo,
    unsigned short* __restrict__ W1, unsigned short* __restrict__ W2) {
  int bx = blockIdx.x, t = threadIdx.x;
  if (bx < 384) {
    int n = bx;
    Wq[n*128 + t] = f2bf(qkv_w[(size_t)t*384 + n]);
  } else if (bx < 512) {
    int n = bx - 384;
    Wo[n*128 + t] = f2bf(wo_w[(size_t)t*128 + n]);
  } else if (bx < 896) {
    int n = bx - 512;
    W1[n*128 + t] = f2bf(mlp_w1[(size_t)t*384 + n]);
  } else {
    int n = bx - 896;
    for (int k = t; k < 384; k += 128)
      W2[n*384 + k] = f2bf(mlp_w2[(size_t)k*128 + n]);
  }
}

// ---------------------------------------------------------------------------
// K1: x(NCHW) -> xh(NHWC) = x + dwconv3x3(x)
// ---------------------------------------------------------------------------
__global__ __launch_bounds__(256) void k_posconv(const float* __restrict__ x,
    const float* __restrict__ pw, const float* __restrict__ pb,
    float* __restrict__ xh) {
  int c = blockIdx.x, b = blockIdx.y;
  const float* xp = x + ((size_t)(b*CH + c))*(HGT*WID);
  float w[9];
#pragma unroll
  for (int i = 0; i < 9; i++) w[i] = pw[c*9 + i];
  float bias = pb[c];
  float* xhb = xh + (size_t)b*HGT*WID*CH + c;
  for (int pix = threadIdx.x; pix < HGT*WID; pix += 256) {
    int h = pix / WID, wv = pix - h*WID;
    float s = bias + xp[pix];
#pragma unroll
    for (int dy = 0; dy < 3; dy++) {
      int hy = h + dy - 1; if ((unsigned)hy >= HGT) continue;
#pragma unroll
      for (int dx = 0; dx < 3; dx++) {
        int wx = wv + dx - 1; if ((unsigned)wx >= WID) continue;
        s += xp[hy*WID + wx] * w[dy*3 + dx];
      }
    }
    xhb[(size_t)pix*CH] = s;
  }
}

// ---------------------------------------------------------------------------
// K2/K8: fused LN + MFMA GEMM. M-tile 128, N=384 (3 chunks of 128), K=128.
// ---------------------------------------------------------------------------
__global__ __launch_bounds__(256, 2) void k_ln_gemm_mfma(
    const float* __restrict__ in, const float* __restrict__ g,
    const float* __restrict__ be, const unsigned short* __restrict__ Wt,
    const float* __restrict__ bias, float* __restrict__ out, int do_gelu) {
  __shared__ __align__(16) unsigned short aL[128*136];
  __shared__ __align__(16) unsigned short bL[128*136];
  size_t base = (size_t)blockIdx.x * 128;
  int t = threadIdx.x;
  { // ---- LN + A-stage: threads 2r, 2r+1 handle row r halves ----
    int r = t >> 1, half = t & 1;
    const float4* src = (const float4*)(in + (base + r)*CH + half*64);
    float v[64];
    float s = 0.f, ss = 0.f;
#pragma unroll
    for (int i = 0; i < 16; i++) {
      float4 f = src[i];
      v[4*i] = f.x; v[4*i+1] = f.y; v[4*i+2] = f.z; v[4*i+3] = f.w;
      s += f.x + f.y + f.z + f.w;
      ss += f.x*f.x + f.y*f.y + f.z*f.z + f.w*f.w;
    }
    s += __shfl_xor(s, 1); ss += __shfl_xor(ss, 1);
    float m  = s * (1.f/128.f);
    float var = ss * (1.f/128.f) - m*m;
    float rs = rsqrtf(var + 1e-6f);
    union { unsigned short us[8]; int4 v4; } pk;
#pragma unroll
    for (int c8 = 0; c8 < 8; c8++) {
#pragma unroll
      for (int j = 0; j < 8; j++) {
        int ch = half*64 + c8*8 + j;
        pk.us[j] = f2bf((v[c8*8 + j] - m) * rs * g[ch] + be[ch]);
      }
      *(int4*)&aL[r*136 + half*64 + c8*8] = pk.v4;
    }
  }
  int wid = t >> 6, lane = t & 63;
  int ln = lane & 15, q = lane >> 4;
  int wr = (wid >> 1)*64, wc = (wid & 1)*64;
  for (int chunk = 0; chunk < 3; chunk++) {
    if (chunk) __syncthreads();
    for (int i = t; i < 2048; i += 256) {
      int row = i >> 4, seg = i & 15;
      *(int4*)&bL[row*136 + seg*8] =
          *(const int4*)(Wt + (size_t)(chunk*128 + row)*128 + seg*8);
    }
    __syncthreads();
    float4v acc[4][4];
#pragma unroll
    for (int a = 0; a < 4; a++)
#pragma unroll
      for (int b = 0; b < 4; b++)
        acc[a][b] = (float4v){0.f, 0.f, 0.f, 0.f};
#pragma unroll
    for (int kk = 0; kk < 4; kk++) {
      int ko = kk*32 + q*8;
      short8 af[4], bf[4];
#pragma unroll
      for (int mf = 0; mf < 4; mf++)
        af[mf] = *(const short8*)&aL[(wr + mf*16 + ln)*136 + ko];
#pragma unroll
      for (int nf = 0; nf < 4; nf++)
        bf[nf] = *(const short8*)&bL[(wc + nf*16 + ln)*136 + ko];
#pragma unroll
      for (int mf = 0; mf < 4; mf++)
#pragma unroll
        for (int nf = 0; nf < 4; nf++)
          acc[mf][nf] = __builtin_amdgcn_mfma_f32_16x16x32_bf16(
              af[mf], bf[nf], acc[mf][nf], 0, 0, 0);
    }
#pragma unroll
    for (int mf = 0; mf < 4; mf++)
#pragma unroll
      for (int nf = 0; nf < 4; nf++) {
        int row = wr + mf*16 + q*4;
        int col = wc + nf*16 + ln + chunk*128;
        float b4 = bias[col];
#pragma unroll
        for (int j = 0; j < 4; j++) {
          float vv = acc[mf][nf][j] + b4;
          if (do_gelu) vv = 0.5f * vv * (1.f + erff(vv * 0.70710678118654752f));
          out[(base + row + j)*NQKV + col] = vv;
        }
      }
  }
}

// ---------------------------------------------------------------------------
// K_vt: vT[b][c][hw] bf16  <- qkv cols [256,384) (LDS-tiled transpose)
// ---------------------------------------------------------------------------
__global__ __launch_bounds__(256) void k_vt(const float* __restrict__ qkv,
    unsigned short* __restrict__ vT) {
  __shared__ unsigned short tile[128*40];
  int pg0 = blockIdx.x * 32;
  int b = pg0 / (HGT*WID), sp0 = pg0 % (HGT*WID);
  int t = threadIdx.x;
  {
    int pl = t >> 3, cg = t & 7;
    const float4* src = (const float4*)(qkv + (size_t)(pg0 + pl)*NQKV + 256 + cg*16);
#pragma unroll
    for (int i = 0; i < 4; i++) {
      float4 f = src[i];
      int c = cg*16 + i*4;
      tile[(c+0)*40 + pl] = f2bf(f.x);
      tile[(c+1)*40 + pl] = f2bf(f.y);
      tile[(c+2)*40 + pl] = f2bf(f.z);
      tile[(c+3)*40 + pl] = f2bf(f.w);
    }
  }
  __syncthreads();
  int c = t >> 1, half = t & 1;
  unsigned short* dst = vT + ((size_t)b*CH + c)*(HGT*WID) + sp0 + half*16;
  const int4* srcl = (const int4*)&tile[c*40 + half*16];
  ((int4*)dst)[0] = srcl[0];
  ((int4*)dst)[1] = srcl[1];
}

// ---------------------------------------------------------------------------
// K3: window means — wave-wide float4 loads (1 KB/instr), LDS cross-wave sum
// grid B*P2, 256 thr. wave w sums pixels w*16..w*16+15; lane = 4-ch group.
// ---------------------------------------------------------------------------
__global__ __launch_bounds__(256) void k_winmean(const float* __restrict__ qkv,
    float* __restrict__ qwin, float* __restrict__ kwin) {
  __shared__ float4 red[4][64];
  int bp = blockIdx.x; int b = bp / P2, p = bp % P2;
  int wy = p / NWIN, wx = p % NWIN;
  int w = threadIdx.x >> 6, l = threadIdx.x & 63;
  float4 acc = make_float4(0.f, 0.f, 0.f, 0.f);
#pragma unroll
  for (int i = 0; i < 16; i++) {
    int pix = w*16 + i;
    int ir = pix >> 3, iw = pix & 7;
    size_t po = (((size_t)b*HGT + wy*8 + ir)*WID + wx*8 + iw)*NQKV;
    float4 v = ((const float4*)(qkv + po))[l];
    acc.x += v.x; acc.y += v.y; acc.z += v.z; acc.w += v.w;
  }
  red[w][l] = acc;
  __syncthreads();
  if (w == 0) {
    float4 t0 = red[0][l], t1 = red[1][l], t2 = red[2][l], t3 = red[3][l];
    float4 s = make_float4((t0.x+t1.x+t2.x+t3.x)*(1.f/64.f),
                           (t0.y+t1.y+t2.y+t3.y)*(1.f/64.f),
                           (t0.z+t1.z+t2.z+t3.z)*(1.f/64.f),
                           (t0.w+t1.w+t2.w+t3.w)*(1.f/64.f));
    if (l < 32) ((float4*)(qwin + (size_t)bp*128))[l] = s;
    else        ((float4*)(kwin + (size_t)bp*128))[l - 32] = s;
  }
}

// ---------------------------------------------------------------------------
// K4: routing logits (49x49 per image) + top-4
// ---------------------------------------------------------------------------
__global__ __launch_bounds__(64) void k_topk(const float* __restrict__ qwin,
    const float* __restrict__ kwin, int* __restrict__ idx) {
  int b = blockIdx.x;
  int p = threadIdx.x;
  float logits[P2];
#pragma unroll
  for (int q = 0; q < P2; q++) logits[q] = 0.f;
  const float* qp = qwin + ((size_t)b*P2 + (p < P2 ? p : 0))*128;
  const float* kp = kwin + (size_t)b*P2*128;
  for (int cc = 0; cc < 32; cc++) {
    float4 qv = ((const float4*)qp)[cc];
#pragma unroll
    for (int q = 0; q < P2; q++) {
      float4 kv = ((const float4*)(kp + q*128))[cc];
      logits[q] += qv.x*kv.x + qv.y*kv.y + qv.z*kv.z + qv.w*kv.w;
    }
  }
  if (p < P2) {
    unsigned long long used = 0ULL;
    for (int t = 0; t < TOPK; t++) {
      float best = -1e30f; int bi = 0;
#pragma unroll
      for (int q = 0; q < P2; q++) {
        bool ok = !((used >> q) & 1ULL);
        if (ok && logits[q] > best) { best = logits[q]; bi = q; }
      }
      used |= 1ULL << bi;
      idx[((size_t)b*P2 + p)*TOPK + t] = bi;
    }
  }
}

// ---------------------------------------------------------------------------
// K5: MFMA attention (unchanged from round 3)
// ---------------------------------------------------------------------------
#define PLS 72
__global__ __launch_bounds__(256) void k_attn_mfma(
    const float* __restrict__ qkv, const unsigned short* __restrict__ vT,
    const int* __restrict__ idx, float* __restrict__ o) {
  __shared__ unsigned short pL[4][64*PLS];
  int bp = blockIdx.x; int b = bp / P2, p = bp % P2;
  int wy = p / NWIN, wx = p % NWIN;
  int h = threadIdx.x >> 6, lane = threadIdx.x & 63;
  int ln = lane & 15, q = lane >> 4;

  short8 aq[4];
#pragma unroll
  for (int mf = 0; mf < 4; mf++) {
    int pq = mf*16 + ln;
    const float* qp = qkv + (((size_t)b*HGT + wy*8 + (pq>>3))*WID + wx*8 + (pq&7))*NQKV + h*32 + q*8;
    float4 f0 = *(const float4*)qp, f1 = *(const float4*)(qp + 4);
    f0.x *= ATT_SCALE; f0.y *= ATT_SCALE; f0.z *= ATT_SCALE; f0.w *= ATT_SCALE;
    f1.x *= ATT_SCALE; f1.y *= ATT_SCALE; f1.z *= ATT_SCALE; f1.w *= ATT_SCALE;
    aq[mf] = cvt8(f0, f1);
  }

  float m_run[4][4], l_run[4][4];
  float4v facc[4][2];
#pragma unroll
  for (int mf = 0; mf < 4; mf++) {
#pragma unroll
    for (int j = 0; j < 4; j++) { m_run[mf][j] = -1e30f; l_run[mf][j] = 0.f; }
    facc[mf][0] = (float4v){0.f,0.f,0.f,0.f};
    facc[mf][1] = (float4v){0.f,0.f,0.f,0.f};
  }

  unsigned short* myP = &pL[h][0];
  int swr = ((ln >> 2) & 3) * 16;

  for (int r = 0; r < TOPK; r++) {
    int win = idx[(size_t)bp*TOPK + r];
    int sy = win / NWIN, sx = win % NWIN;
    short8 bk[4];
#pragma unroll
    for (int nf = 0; nf < 4; nf++) {
      int kp = nf*16 + ln;
      const float* kpp = qkv + (((size_t)b*HGT + sy*8 + (kp>>3))*WID + sx*8 + (kp&7))*NQKV + 128 + h*32 + q*8;
      bk[nf] = cvt8(*(const float4*)kpp, *(const float4*)(kpp + 4));
    }
    float4v sacc[4][4];
#pragma unroll
    for (int mf = 0; mf < 4; mf++)
#pragma unroll
      for (int nf = 0; nf < 4; nf++)
        sacc[mf][nf] = (float4v){0.f,0.f,0.f,0.f};
#pragma unroll
    for (int mf = 0; mf < 4; mf++)
#pragma unroll
      for (int nf = 0; nf < 4; nf++)
        sacc[mf][nf] = __builtin_amdgcn_mfma_f32_16x16x32_bf16(
            aq[mf], bk[nf], sacc[mf][nf], 0, 0, 0);
#pragma unroll
    for (int mf = 0; mf < 4; mf++) {
#pragma unroll
      for (int j = 0; j < 4; j++) {
        float s0 = sacc[mf][0][j], s1 = sacc[mf][1][j];
        float s2 = sacc[mf][2][j], s3 = sacc[mf][3][j];
        float mx = fmaxf(fmaxf(s0, s1), fmaxf(s2, s3));
        mx = fmaxf(mx, __shfl_xor(mx, 1));
        mx = fmaxf(mx, __shfl_xor(mx, 2));
        mx = fmaxf(mx, __shfl_xor(mx, 4));
        mx = fmaxf(mx, __shfl_xor(mx, 8));
        float mo = m_run[mf][j];
        float mn = fmaxf(mo, mx);
        float corr = __expf(mo - mn);
        m_run[mf][j] = mn;
        float e0 = __expf(s0 - mn), e1 = __expf(s1 - mn);
        float e2 = __expf(s2 - mn), e3 = __expf(s3 - mn);
        float ls = e0 + e1 + e2 + e3;
        ls += __shfl_xor(ls, 1);
        ls += __shfl_xor(ls, 2);
        ls += __shfl_xor(ls, 4);
        ls += __shfl_xor(ls, 8);
        l_run[mf][j] = l_run[mf][j]*corr + ls;
        facc[mf][0][j] *= corr; facc[mf][1][j] *= corr;
        int rowoff = (mf*16 + q*4 + j)*PLS;
        int sww = q*16;
        myP[rowoff + (( 0 + ln) ^ sww)] = f2bf(e0);
        myP[rowoff + ((16 + ln) ^ sww)] = f2bf(e1);
        myP[rowoff + ((32 + ln) ^ sww)] = f2bf(e2);
        myP[rowoff + ((48 + ln) ^ sww)] = f2bf(e3);
      }
    }
#pragma unroll
    for (int kk = 0; kk < 2; kk++) {
      short8 ap[4];
#pragma unroll
      for (int mf = 0; mf < 4; mf++)
        ap[mf] = *(const short8*)&myP[(mf*16 + ln)*PLS + ((kk*32 + q*8) ^ swr)];
      short8 bv[2];
#pragma unroll
      for (int nf2 = 0; nf2 < 2; nf2++) {
        int d = h*32 + nf2*16 + ln;
        int K0 = kk*32 + q*8;
        const unsigned short* vp = vT + ((size_t)b*CH + d)*(HGT*WID)
            + (sy*8 + (K0 >> 3))*WID + sx*8;
        bv[nf2] = *(const short8*)vp;
      }
#pragma unroll
      for (int mf = 0; mf < 4; mf++)
#pragma unroll
        for (int nf2 = 0; nf2 < 2; nf2++)
          facc[mf][nf2] = __builtin_amdgcn_mfma_f32_16x16x32_bf16(
              ap[mf], bv[nf2], facc[mf][nf2], 0, 0, 0);
    }
  }
#pragma unroll
  for (int mf = 0; mf < 4; mf++)
#pragma unroll
    for (int j = 0; j < 4; j++) {
      float inv = 1.f / l_run[mf][j];
      int prow = mf*16 + q*4 + j;
      size_t pg = ((size_t)b*HGT + wy*8 + (prow>>3))*WID + wx*8 + (prow&7);
      o[pg*CH + h*32 + ln]      = facc[mf][0][j] * inv;
      o[pg*CH + h*32 + 16 + ln] = facc[mf][1][j] * inv;
    }
}

// ---------------------------------------------------------------------------
// K6: o += dwconv5x5(v) + lepe_b  — LDS-staged from planar bf16 vT.
// block = (b, rowgroup of 8, chgroup of 32); LDS halo tile 12x60x32 bf16.
// 5-wide sliding window: 5 ds_read_u16 + 25 FMA per output.
// ---------------------------------------------------------------------------
__global__ __launch_bounds__(256) void k_lepe(const unsigned short* __restrict__ vT,
    const float* __restrict__ lw, const float* __restrict__ lb,
    float* __restrict__ o) {
  __shared__ unsigned short sh[12*60*32];   // [rr][col][c] 46 KB
  int b = blockIdx.y;
  int rg = blockIdx.x >> 2, cg = blockIdx.x & 3;
  int row0 = rg*8, c0 = cg*32;
  int t = threadIdx.x;
  // zero (halo default)
  for (int i = t; i < 12*60*32/8; i += 256)
    ((int4*)sh)[i] = make_int4(0,0,0,0);
  __syncthreads();
  // stage valid region: 32 c x 12 rows x 7 chunks of 8 cols
  for (int i = t; i < 2688; i += 256) {
    int chunk = i % 7, rr = (i/7) % 12, c = i / 84;
    int grow = row0 + rr - 2;
    if ((unsigned)grow < HGT) {
      int4 v = *(const int4*)(vT + ((size_t)(b*CH + c0 + c))*(HGT*WID) + grow*WID + chunk*8);
      union { int4 v4; unsigned short us[8]; } u; u.v4 = v;
#pragma unroll
      for (int j = 0; j < 8; j++)
        sh[(rr*60 + 2 + chunk*8 + j)*32 + c] = u.us[j];
    }
  }
  __syncthreads();
  int c = t & 31, pg = t >> 5;     // channel-in-group, output row 0..7
  float w[25];
#pragma unroll
  for (int i = 0; i < 25; i++) w[i] = lw[(c0 + c)*25 + i];
  float bias = lb[c0 + c];
  const unsigned short* rowp[5];
#pragma unroll
  for (int dy = 0; dy < 5; dy++) rowp[dy] = &sh[((pg + dy)*60)*32 + c];
  float win[5][5];                 // [slot][dy]
#pragma unroll
  for (int j = 0; j < 4; j++)
#pragma unroll
    for (int dy = 0; dy < 5; dy++) win[j][dy] = bf2f(rowp[dy][j*32]);
  float* ob = &o[(((size_t)b*HGT + row0 + pg)*WID)*CH + c0 + c];
#pragma unroll
  for (int col = 0; col < 56; col++) {
    int slot = (col + 4) % 5;
#pragma unroll
    for (int dy = 0; dy < 5; dy++) win[slot][dy] = bf2f(rowp[dy][(col + 4)*32]);
    float s = bias;
#pragma unroll
    for (int dx = 0; dx < 5; dx++) {
      int sl = (col + dx) % 5;
#pragma unroll
      for (int dy = 0; dy < 5; dy++) s += win[sl][dy] * w[dy*5 + dx];
    }
    ob[col*CH] += s;
  }
}

// ---------------------------------------------------------------------------
// K7: xh += in @ wo + wo_b  (K=128, N=128) via MFMA
// ---------------------------------------------------------------------------
__global__ __launch_bounds__(256, 2) void k_wo_mfma(
    const float* __restrict__ in, const unsigned short* __restrict__ Wt,
    const float* __restrict__ bias, float* __restrict__ xh) {
  __shared__ __align__(16) unsigned short aL[128*136];
  __shared__ __align__(16) unsigned short bL[128*136];
  size_t base = (size_t)blockIdx.x * 128;
  int t = threadIdx.x;
  {
    int r = t >> 1, half = t & 1;
    const float4* src = (const float4*)(in + (base + r)*CH + half*64);
    union { unsigned short us[8]; int4 v4; } pk;
#pragma unroll
    for (int c8 = 0; c8 < 8; c8++) {
      float4 f0 = src[c8*2], f1 = src[c8*2 + 1];
      pk.us[0] = f2bf(f0.x); pk.us[1] = f2bf(f0.y);
      pk.us[2] = f2bf(f0.z); pk.us[3] = f2bf(f0.w);
      pk.us[4] = f2bf(f1.x); pk.us[5] = f2bf(f1.y);
      pk.us[6] = f2bf(f1.z); pk.us[7] = f2bf(f1.w);
      *(int4*)&aL[r*136 + half*64 + c8*8] = pk.v4;
    }
  }
  for (int i = t; i < 2048; i += 256) {
    int row = i >> 4, seg = i & 15;
    *(int4*)&bL[row*136 + seg*8] = *(const int4*)(Wt + (size_t)row*128 + seg*8);
  }
  __syncthreads();
  int wid = t >> 6, lane = t & 63;
  int ln = lane & 15, q = lane >> 4;
  int wr = (wid >> 1)*64, wc = (wid & 1)*64;
  float4v acc[4][4];
#pragma unroll
  for (int a = 0; a < 4; a++)
#pragma unroll
    for (int b = 0; b < 4; b++)
      acc[a][b] = (float4v){0.f, 0.f, 0.f, 0.f};
#pragma unroll
  for (int kk = 0; kk < 4; kk++) {
    int ko = kk*32 + q*8;
    short8 af[4], bf[4];
#pragma unroll
    for (int mf = 0; mf < 4; mf++)
      af[mf] = *(const short8*)&aL[(wr + mf*16 + ln)*136 + ko];
#pragma unroll
    for (int nf = 0; nf < 4; nf++)
      bf[nf] = *(const short8*)&bL[(wc + nf*16 + ln)*136 + ko];
#pragma unroll
    for (int mf = 0; mf < 4; mf++)
#pragma unroll
      for (int nf = 0; nf < 4; nf++)
        acc[mf][nf] = __builtin_amdgcn_mfma_f32_16x16x32_bf16(
            af[mf], bf[nf], acc[mf][nf], 0, 0, 0);
  }
#pragma unroll
  for (int mf = 0; mf < 4; mf++)
#pragma unroll
    for (int nf = 0; nf < 4; nf++) {
      int row = wr + mf*16 + q*4;
      int col = wc + nf*16 + ln;
      float b4 = bias[col];
#pragma unroll
      for (int j = 0; j < 4; j++) {
        float* p = &xh[(base + row + j)*CH + col];
        *p += acc[mf][nf][j] + b4;
      }
    }
}

// ---------------------------------------------------------------------------
// K9: out(NCHW) = xh + hid @ mlp_w2 + mlp_b2  (K=384 in 3 chunks, N=128)
// ---------------------------------------------------------------------------
__global__ __launch_bounds__(256, 2) void k_mlp2_mfma(
    const float* __restrict__ hid, const unsigned short* __restrict__ Wt,
    const float* __restrict__ bias, const float* __restrict__ xh,
    float* __restrict__ out) {
  __shared__ __align__(16) unsigned short aL[128*136];
  __shared__ __align__(16) unsigned short bL[128*136];
  size_t base = (size_t)blockIdx.x * 128;
  int t = threadIdx.x;
  int wid = t >> 6, lane = t & 63;
  int ln = lane & 15, q = lane >> 4;
  int wr = (wid >> 1)*64, wc = (wid & 1)*64;
  float4v acc[4][4];
#pragma unroll
  for (int a = 0; a < 4; a++)
#pragma unroll
    for (int b = 0; b < 4; b++)
      acc[a][b] = (float4v){0.f, 0.f, 0.f, 0.f};
  for (int kc = 0; kc < 3; kc++) {
    if (kc) __syncthreads();
    {
      int r = t >> 1, half = t & 1;
      const float4* src = (const float4*)(hid + (base + r)*NQKV + kc*128 + half*64);
      union { unsigned short us[8]; int4 v4; } pk;
#pragma unroll
      for (int c8 = 0; c8 < 8; c8++) {
        float4 f0 = src[c8*2], f1 = src[c8*2 + 1];
        pk.us[0] = f2bf(f0.x); pk.us[1] = f2bf(f0.y);
        pk.us[2] = f2bf(f0.z); pk.us[3] = f2bf(f0.w);
        pk.us[4] = f2bf(f1.x); pk.us[5] = f2bf(f1.y);
        pk.us[6] = f2bf(f1.z); pk.us[7] = f2bf(f1.w);
        *(int4*)&aL[r*136 + half*64 + c8*8] = pk.v4;
      }
    }
    for (int i = t; i < 2048; i += 256) {
      int row = i >> 4, seg = i & 15;
      *(int4*)&bL[row*136 + seg*8] =
          *(const int4*)(Wt + (size_t)row*NQKV + kc*128 + seg*8);
    }
    __syncthreads();
#pragma unroll
    for (int kk = 0; kk < 4; kk++) {
      int ko = kk*32 + q*8;
      short8 af[4], bf[4];
#pragma unroll
      for (int mf = 0; mf < 4; mf++)
        af[mf] = *(const short8*)&aL[(wr + mf*16 + ln)*136 + ko];
#pragma unroll
      for (int nf = 0; nf < 4; nf++)
        bf[nf] = *(const short8*)&bL[(wc + nf*16 + ln)*136 + ko];
#pragma unroll
      for (int mf = 0; mf < 4; mf++)
#pragma unroll
        for (int nf = 0; nf < 4; nf++)
          acc[mf][nf] = __builtin_amdgcn_mfma_f32_16x16x32_bf16(
              af[mf], bf[nf], acc[mf][nf], 0, 0, 0);
    }
  }
#pragma unroll
  for (int mf = 0; mf < 4; mf++)
#pragma unroll
    for (int nf = 0; nf < 4; nf++) {
      int row = wr + mf*16 + q*4;
      int col = wc + nf*16 + ln;
      float b4 = bias[col];
#pragma unroll
      for (int j = 0; j < 4; j++) {
        size_t pixel = base + row + j;
        int b = (int)(pixel / (HGT*WID));
        int sp = (int)(pixel % (HGT*WID));
        out[((size_t)b*CH + col)*(HGT*WID) + sp] =
            acc[mf][nf][j] + b4 + xh[pixel*CH + col];
      }
    }
}

// ---------------------------------------------------------------------------
extern "C" void kernel_launch(void* const* d_in, const int* in_sizes, int n_in,
                              void* d_out, int out_size, void* d_ws, size_t ws_size,
                              hipStream_t stream) {
  const float* x      = (const float*)d_in[0];
  const float* pos_w  = (const float*)d_in[1];
  const float* pos_b  = (const float*)d_in[2];
  const float* ln1_g  = (const float*)d_in[3];
  const float* ln1_b  = (const float*)d_in[4];
  const float* qkv_w  = (const float*)d_in[5];
  const float* qkv_b  = (const float*)d_in[6];
  const float* lepe_w = (const float*)d_in[7];
  const float* lepe_b = (const float*)d_in[8];
  const float* wo_w   = (const float*)d_in[9];
  const float* wo_b   = (const float*)d_in[10];
  const float* ln2_g  = (const float*)d_in[11];
  const float* ln2_b  = (const float*)d_in[12];
  const float* mlp_w1 = (const float*)d_in[13];
  const float* mlp_b1 = (const float*)d_in[14];
  const float* mlp_w2 = (const float*)d_in[15];
  const float* mlp_b2 = (const float*)d_in[16];

  float* ws   = (float*)d_ws;
  float* xh   = ws;                          // NPIX*128
  float* qkv  = xh  + (size_t)NPIX*CH;       // NPIX*384
  float* o    = qkv + (size_t)NPIX*NQKV;     // NPIX*128
  float* qwin = o   + (size_t)NPIX*CH;       // B*49*128
  float* kwin = qwin + (size_t)BATCH*P2*128; // B*49*128
  int*   idx  = (int*)(kwin + (size_t)BATCH*P2*128); // B*49*4
  unsigned short* Wq = (unsigned short*)(idx + BATCH*P2*TOPK); // 384*128
  unsigned short* Wo = Wq + 384*128;         // 128*128
  unsigned short* W1 = Wo + 128*128;         // 384*128
  unsigned short* W2 = W1 + 384*128;         // 128*384
  unsigned short* vT = W2 + 128*384;         // NPIX*128 bf16
  float* hid  = qkv;                         // reuse qkv buffer for MLP hidden

  k_prep<<<1024, 128, 0, stream>>>(qkv_w, wo_w, mlp_w1, mlp_w2, Wq, Wo, W1, W2);
  k_posconv<<<dim3(CH, BATCH), 256, 0, stream>>>(x, pos_w, pos_b, xh);
  k_ln_gemm_mfma<<<NPIX/128, 256, 0, stream>>>(xh, ln1_g, ln1_b, Wq, qkv_b, qkv, 0);
  k_vt<<<NPIX/32, 256, 0, stream>>>(qkv, vT);
  k_winmean<<<BATCH*P2, 256, 0, stream>>>(qkv, qwin, kwin);
  k_topk<<<BATCH, 64, 0, stream>>>(qwin, kwin, idx);
  k_attn_mfma<<<BATCH*P2, 256, 0, stream>>>(qkv, vT, idx, o);
  k_lepe<<<dim3(28, BATCH), 256, 0, stream>>>(vT, lepe_w, lepe_b, o);
  k_wo_mfma<<<NPIX/128, 256, 0, stream>>>(o, Wo, wo_b, xh);
  k_ln_gemm_mfma<<<NPIX/128, 256, 0, stream>>>(xh, ln2_g, ln2_b, W1, mlp_b1, hid, 1);
  k_mlp2_mfma<<<NPIX/128, 256, 0, stream>>>(hid, W2, mlp_b2, xh, (float*)d_out);
}

// Round 5
// 476.101 us; speedup vs baseline: 3.0128x; 1.1729x over previous
//
#include <hip/hip_runtime.h>
#include <math.h>

#define BATCH 16
#define CH    128
#define HGT   56
#define WID   56
#define NPIX  (BATCH*HGT*WID)   // 50176
#define NQKV  384
#define NWIN  7
#define P2    49
#define TOPK  4
#define ATT_SCALE 0.088388347648318447f   // 128^-0.5

typedef __attribute__((ext_vector_type(8))) short short8;
typedef __attribute__((ext_vector_type(4))) float float4v;

static __device__ __forceinline__ unsigned short f2bf(float f) {
  unsigned u = __float_as_uint(f);
  u += 0x7fffu + ((u >> 16) & 1u);   // round-to-nearest-even
  return (unsigned short)(u >> 16);
}
static __device__ __forceinline__ float bf2f(unsigned short u) {
  return __uint_as_float((unsigned)u << 16);
}

static __device__ __forceinline__ short8 cvt8(float4 a, float4 b) {
  union { unsigned short us[8]; short8 s8; } u;
  u.us[0] = f2bf(a.x); u.us[1] = f2bf(a.y); u.us[2] = f2bf(a.z); u.us[3] = f2bf(a.w);
  u.us[4] = f2bf(b.x); u.us[5] = f2bf(b.y); u.us[6] = f2bf(b.z); u.us[7] = f2bf(b.w);
  return u.s8;
}

// ---------------------------------------------------------------------------
// K0: weight prep — convert to bf16 and transpose to [N][K] layout.
// ---------------------------------------------------------------------------
__global__ __launch_bounds__(128) void k_prep(
    const float* __restrict__ qkv_w, const float* __restrict__ wo_w,
    const float* __restrict__ mlp_w1, const float* __restrict__ mlp_w2,
    unsigned short* __restrict__ Wq, unsigned short* __restrict__ Wo,
    unsigned short* __restrict__ W1, unsigned short* __restrict__ W2) {
  int bx = blockIdx.x, t = threadIdx.x;
  if (bx < 384) {
    int n = bx;
    Wq[n*128 + t] = f2bf(qkv_w[(size_t)t*384 + n]);
  } else if (bx < 512) {
    int n = bx - 384;
    Wo[n*128 + t] = f2bf(wo_w[(size_t)t*128 + n]);
  } else if (bx < 896) {
    int n = bx - 512;
    W1[n*128 + t] = f2bf(mlp_w1[(size_t)t*384 + n]);
  } else {
    int n = bx - 896;
    for (int k = t; k < 384; k += 128)
      W2[n*384 + k] = f2bf(mlp_w2[(size_t)k*128 + n]);
  }
}

// ---------------------------------------------------------------------------
// K1: x(NCHW) -> xh(NHWC) = x + dwconv3x3(x).  LDS-staged transpose:
// block = (b, rowgroup of 8, chgroup of 32); halo tile 10x58x32 fp32 (74 KB).
// Writes are 128 B-contiguous channel segments (full cache lines) — fixes the
// 10x write amplification of the per-channel-plane version.
// ---------------------------------------------------------------------------
__global__ __launch_bounds__(256) void k_posconv(const float* __restrict__ x,
    const float* __restrict__ pw, const float* __restrict__ pb,
    float* __restrict__ xh) {
  __shared__ float sh[10*58*32];   // [rr][colidx][c], colidx 0 = global col -1
  int b = blockIdx.y;
  int rg = blockIdx.x >> 2, cg = blockIdx.x & 3;
  int row0 = rg*8, c0 = cg*32;
  int t = threadIdx.x;
  for (int i = t; i < 10*58*32/4; i += 256)
    ((int4*)sh)[i] = make_int4(0,0,0,0);
  __syncthreads();
  // stage: 32 ch x 10 rows x 14 float4-chunks
  for (int i = t; i < 4480; i += 256) {
    int c = i & 31, chunk = (i >> 5) % 14, rr = i / 448;
    int grow = row0 + rr - 1;
    if ((unsigned)grow < HGT) {
      float4 v = *(const float4*)(x + ((size_t)(b*CH + c0 + c))*(HGT*WID)
                                  + grow*WID + chunk*4);
      float* d = &sh[(rr*58 + 1 + chunk*4)*32 + c];
      d[0] = v.x; d[32] = v.y; d[64] = v.z; d[96] = v.w;
    }
  }
  __syncthreads();
  int c = t & 31, pg = t >> 5;
  float w[9];
#pragma unroll
  for (int i = 0; i < 9; i++) w[i] = pw[(c0 + c)*9 + i];
  float bias = pb[c0 + c];
  const float* rowp[3];
#pragma unroll
  for (int dy = 0; dy < 3; dy++) rowp[dy] = &sh[((pg + dy)*58)*32 + c];
  float win[3][3];
#pragma unroll
  for (int j = 0; j < 2; j++)
#pragma unroll
    for (int dy = 0; dy < 3; dy++) win[j][dy] = rowp[dy][j*32];
  float* ob = &xh[(((size_t)b*HGT + row0 + pg)*WID)*CH + c0 + c];
#pragma unroll
  for (int col = 0; col < 56; col++) {
    int slot = (col + 2) % 3;
#pragma unroll
    for (int dy = 0; dy < 3; dy++) win[slot][dy] = rowp[dy][(col + 2)*32];
    float s = bias + win[(col + 1) % 3][1];   // + x (center)
#pragma unroll
    for (int dx = 0; dx < 3; dx++) {
      int sl = (col + dx) % 3;
#pragma unroll
      for (int dy = 0; dy < 3; dy++) s += win[sl][dy] * w[dy*3 + dx];
    }
    ob[col*CH] = s;
  }
}

// ---------------------------------------------------------------------------
// K2/K8: fused LN + MFMA GEMM. M-tile 128, N=384 (3 chunks of 128), K=128.
// ---------------------------------------------------------------------------
__global__ __launch_bounds__(256, 2) void k_ln_gemm_mfma(
    const float* __restrict__ in, const float* __restrict__ g,
    const float* __restrict__ be, const unsigned short* __restrict__ Wt,
    const float* __restrict__ bias, float* __restrict__ out, int do_gelu) {
  __shared__ __align__(16) unsigned short aL[128*136];
  __shared__ __align__(16) unsigned short bL[128*136];
  size_t base = (size_t)blockIdx.x * 128;
  int t = threadIdx.x;
  { // ---- LN + A-stage: threads 2r, 2r+1 handle row r halves ----
    int r = t >> 1, half = t & 1;
    const float4* src = (const float4*)(in + (base + r)*CH + half*64);
    float v[64];
    float s = 0.f, ss = 0.f;
#pragma unroll
    for (int i = 0; i < 16; i++) {
      float4 f = src[i];
      v[4*i] = f.x; v[4*i+1] = f.y; v[4*i+2] = f.z; v[4*i+3] = f.w;
      s += f.x + f.y + f.z + f.w;
      ss += f.x*f.x + f.y*f.y + f.z*f.z + f.w*f.w;
    }
    s += __shfl_xor(s, 1); ss += __shfl_xor(ss, 1);
    float m  = s * (1.f/128.f);
    float var = ss * (1.f/128.f) - m*m;
    float rs = rsqrtf(var + 1e-6f);
    union { unsigned short us[8]; int4 v4; } pk;
#pragma unroll
    for (int c8 = 0; c8 < 8; c8++) {
#pragma unroll
      for (int j = 0; j < 8; j++) {
        int ch = half*64 + c8*8 + j;
        pk.us[j] = f2bf((v[c8*8 + j] - m) * rs * g[ch] + be[ch]);
      }
      *(int4*)&aL[r*136 + half*64 + c8*8] = pk.v4;
    }
  }
  int wid = t >> 6, lane = t & 63;
  int ln = lane & 15, q = lane >> 4;
  int wr = (wid >> 1)*64, wc = (wid & 1)*64;
  for (int chunk = 0; chunk < 3; chunk++) {
    if (chunk) __syncthreads();
    for (int i = t; i < 2048; i += 256) {
      int row = i >> 4, seg = i & 15;
      *(int4*)&bL[row*136 + seg*8] =
          *(const int4*)(Wt + (size_t)(chunk*128 + row)*128 + seg*8);
    }
    __syncthreads();
    float4v acc[4][4];
#pragma unroll
    for (int a = 0; a < 4; a++)
#pragma unroll
      for (int b = 0; b < 4; b++)
        acc[a][b] = (float4v){0.f, 0.f, 0.f, 0.f};
#pragma unroll
    for (int kk = 0; kk < 4; kk++) {
      int ko = kk*32 + q*8;
      short8 af[4], bf[4];
#pragma unroll
      for (int mf = 0; mf < 4; mf++)
        af[mf] = *(const short8*)&aL[(wr + mf*16 + ln)*136 + ko];
#pragma unroll
      for (int nf = 0; nf < 4; nf++)
        bf[nf] = *(const short8*)&bL[(wc + nf*16 + ln)*136 + ko];
#pragma unroll
      for (int mf = 0; mf < 4; mf++)
#pragma unroll
        for (int nf = 0; nf < 4; nf++)
          acc[mf][nf] = __builtin_amdgcn_mfma_f32_16x16x32_bf16(
              af[mf], bf[nf], acc[mf][nf], 0, 0, 0);
    }
#pragma unroll
    for (int mf = 0; mf < 4; mf++)
#pragma unroll
      for (int nf = 0; nf < 4; nf++) {
        int row = wr + mf*16 + q*4;
        int col = wc + nf*16 + ln + chunk*128;
        float b4 = bias[col];
#pragma unroll
        for (int j = 0; j < 4; j++) {
          float vv = acc[mf][nf][j] + b4;
          if (do_gelu) vv = 0.5f * vv * (1.f + erff(vv * 0.70710678118654752f));
          out[(base + row + j)*NQKV + col] = vv;
        }
      }
  }
}

// ---------------------------------------------------------------------------
// K_vt: vT[b][c][hw] bf16  <- qkv cols [256,384) (LDS-tiled transpose)
// ---------------------------------------------------------------------------
__global__ __launch_bounds__(256) void k_vt(const float* __restrict__ qkv,
    unsigned short* __restrict__ vT) {
  __shared__ unsigned short tile[128*40];
  int pg0 = blockIdx.x * 32;
  int b = pg0 / (HGT*WID), sp0 = pg0 % (HGT*WID);
  int t = threadIdx.x;
  {
    int pl = t >> 3, cg = t & 7;
    const float4* src = (const float4*)(qkv + (size_t)(pg0 + pl)*NQKV + 256 + cg*16);
#pragma unroll
    for (int i = 0; i < 4; i++) {
      float4 f = src[i];
      int c = cg*16 + i*4;
      tile[(c+0)*40 + pl] = f2bf(f.x);
      tile[(c+1)*40 + pl] = f2bf(f.y);
      tile[(c+2)*40 + pl] = f2bf(f.z);
      tile[(c+3)*40 + pl] = f2bf(f.w);
    }
  }
  __syncthreads();
  int c = t >> 1, half = t & 1;
  unsigned short* dst = vT + ((size_t)b*CH + c)*(HGT*WID) + sp0 + half*16;
  const int4* srcl = (const int4*)&tile[c*40 + half*16];
  ((int4*)dst)[0] = srcl[0];
  ((int4*)dst)[1] = srcl[1];
}

// ---------------------------------------------------------------------------
// K3: window means — wave-wide float4 loads, LDS cross-wave sum
// ---------------------------------------------------------------------------
__global__ __launch_bounds__(256) void k_winmean(const float* __restrict__ qkv,
    float* __restrict__ qwin, float* __restrict__ kwin) {
  __shared__ float4 red[4][64];
  int bp = blockIdx.x; int b = bp / P2, p = bp % P2;
  int wy = p / NWIN, wx = p % NWIN;
  int w = threadIdx.x >> 6, l = threadIdx.x & 63;
  float4 acc = make_float4(0.f, 0.f, 0.f, 0.f);
#pragma unroll
  for (int i = 0; i < 16; i++) {
    int pix = w*16 + i;
    int ir = pix >> 3, iw = pix & 7;
    size_t po = (((size_t)b*HGT + wy*8 + ir)*WID + wx*8 + iw)*NQKV;
    float4 v = ((const float4*)(qkv + po))[l];
    acc.x += v.x; acc.y += v.y; acc.z += v.z; acc.w += v.w;
  }
  red[w][l] = acc;
  __syncthreads();
  if (w == 0) {
    float4 t0 = red[0][l], t1 = red[1][l], t2 = red[2][l], t3 = red[3][l];
    float4 s = make_float4((t0.x+t1.x+t2.x+t3.x)*(1.f/64.f),
                           (t0.y+t1.y+t2.y+t3.y)*(1.f/64.f),
                           (t0.z+t1.z+t2.z+t3.z)*(1.f/64.f),
                           (t0.w+t1.w+t2.w+t3.w)*(1.f/64.f));
    if (l < 32) ((float4*)(qwin + (size_t)bp*128))[l] = s;
    else        ((float4*)(kwin + (size_t)bp*128))[l - 32] = s;
  }
}

// ---------------------------------------------------------------------------
// K4: routing logits (49x49 per image) + top-4
// ---------------------------------------------------------------------------
__global__ __launch_bounds__(64) void k_topk(const float* __restrict__ qwin,
    const float* __restrict__ kwin, int* __restrict__ idx) {
  int b = blockIdx.x;
  int p = threadIdx.x;
  float logits[P2];
#pragma unroll
  for (int q = 0; q < P2; q++) logits[q] = 0.f;
  const float* qp = qwin + ((size_t)b*P2 + (p < P2 ? p : 0))*128;
  const float* kp = kwin + (size_t)b*P2*128;
  for (int cc = 0; cc < 32; cc++) {
    float4 qv = ((const float4*)qp)[cc];
#pragma unroll
    for (int q = 0; q < P2; q++) {
      float4 kv = ((const float4*)(kp + q*128))[cc];
      logits[q] += qv.x*kv.x + qv.y*kv.y + qv.z*kv.z + qv.w*kv.w;
    }
  }
  if (p < P2) {
    unsigned long long used = 0ULL;
    for (int t = 0; t < TOPK; t++) {
      float best = -1e30f; int bi = 0;
#pragma unroll
      for (int q = 0; q < P2; q++) {
        bool ok = !((used >> q) & 1ULL);
        if (ok && logits[q] > best) { best = logits[q]; bi = q; }
      }
      used |= 1ULL << bi;
      idx[((size_t)b*P2 + p)*TOPK + t] = bi;
    }
  }
}

// ---------------------------------------------------------------------------
// K5: MFMA attention
// ---------------------------------------------------------------------------
#define PLS 72
__global__ __launch_bounds__(256) void k_attn_mfma(
    const float* __restrict__ qkv, const unsigned short* __restrict__ vT,
    const int* __restrict__ idx, float* __restrict__ o) {
  __shared__ unsigned short pL[4][64*PLS];
  int bp = blockIdx.x; int b = bp / P2, p = bp % P2;
  int wy = p / NWIN, wx = p % NWIN;
  int h = threadIdx.x >> 6, lane = threadIdx.x & 63;
  int ln = lane & 15, q = lane >> 4;

  short8 aq[4];
#pragma unroll
  for (int mf = 0; mf < 4; mf++) {
    int pq = mf*16 + ln;
    const float* qp = qkv + (((size_t)b*HGT + wy*8 + (pq>>3))*WID + wx*8 + (pq&7))*NQKV + h*32 + q*8;
    float4 f0 = *(const float4*)qp, f1 = *(const float4*)(qp + 4);
    f0.x *= ATT_SCALE; f0.y *= ATT_SCALE; f0.z *= ATT_SCALE; f0.w *= ATT_SCALE;
    f1.x *= ATT_SCALE; f1.y *= ATT_SCALE; f1.z *= ATT_SCALE; f1.w *= ATT_SCALE;
    aq[mf] = cvt8(f0, f1);
  }

  float m_run[4][4], l_run[4][4];
  float4v facc[4][2];
#pragma unroll
  for (int mf = 0; mf < 4; mf++) {
#pragma unroll
    for (int j = 0; j < 4; j++) { m_run[mf][j] = -1e30f; l_run[mf][j] = 0.f; }
    facc[mf][0] = (float4v){0.f,0.f,0.f,0.f};
    facc[mf][1] = (float4v){0.f,0.f,0.f,0.f};
  }

  unsigned short* myP = &pL[h][0];
  int swr = ((ln >> 2) & 3) * 16;

  for (int r = 0; r < TOPK; r++) {
    int win = idx[(size_t)bp*TOPK + r];
    int sy = win / NWIN, sx = win % NWIN;
    short8 bk[4];
#pragma unroll
    for (int nf = 0; nf < 4; nf++) {
      int kp = nf*16 + ln;
      const float* kpp = qkv + (((size_t)b*HGT + sy*8 + (kp>>3))*WID + sx*8 + (kp&7))*NQKV + 128 + h*32 + q*8;
      bk[nf] = cvt8(*(const float4*)kpp, *(const float4*)(kpp + 4));
    }
    float4v sacc[4][4];
#pragma unroll
    for (int mf = 0; mf < 4; mf++)
#pragma unroll
      for (int nf = 0; nf < 4; nf++)
        sacc[mf][nf] = (float4v){0.f,0.f,0.f,0.f};
#pragma unroll
    for (int mf = 0; mf < 4; mf++)
#pragma unroll
      for (int nf = 0; nf < 4; nf++)
        sacc[mf][nf] = __builtin_amdgcn_mfma_f32_16x16x32_bf16(
            aq[mf], bk[nf], sacc[mf][nf], 0, 0, 0);
#pragma unroll
    for (int mf = 0; mf < 4; mf++) {
#pragma unroll
      for (int j = 0; j < 4; j++) {
        float s0 = sacc[mf][0][j], s1 = sacc[mf][1][j];
        float s2 = sacc[mf][2][j], s3 = sacc[mf][3][j];
        float mx = fmaxf(fmaxf(s0, s1), fmaxf(s2, s3));
        mx = fmaxf(mx, __shfl_xor(mx, 1));
        mx = fmaxf(mx, __shfl_xor(mx, 2));
        mx = fmaxf(mx, __shfl_xor(mx, 4));
        mx = fmaxf(mx, __shfl_xor(mx, 8));
        float mo = m_run[mf][j];
        float mn = fmaxf(mo, mx);
        float corr = __expf(mo - mn);
        m_run[mf][j] = mn;
        float e0 = __expf(s0 - mn), e1 = __expf(s1 - mn);
        float e2 = __expf(s2 - mn), e3 = __expf(s3 - mn);
        float ls = e0 + e1 + e2 + e3;
        ls += __shfl_xor(ls, 1);
        ls += __shfl_xor(ls, 2);
        ls += __shfl_xor(ls, 4);
        ls += __shfl_xor(ls, 8);
        l_run[mf][j] = l_run[mf][j]*corr + ls;
        facc[mf][0][j] *= corr; facc[mf][1][j] *= corr;
        int rowoff = (mf*16 + q*4 + j)*PLS;
        int sww = q*16;
        myP[rowoff + (( 0 + ln) ^ sww)] = f2bf(e0);
        myP[rowoff + ((16 + ln) ^ sww)] = f2bf(e1);
        myP[rowoff + ((32 + ln) ^ sww)] = f2bf(e2);
        myP[rowoff + ((48 + ln) ^ sww)] = f2bf(e3);
      }
    }
#pragma unroll
    for (int kk = 0; kk < 2; kk++) {
      short8 ap[4];
#pragma unroll
      for (int mf = 0; mf < 4; mf++)
        ap[mf] = *(const short8*)&myP[(mf*16 + ln)*PLS + ((kk*32 + q*8) ^ swr)];
      short8 bv[2];
#pragma unroll
      for (int nf2 = 0; nf2 < 2; nf2++) {
        int d = h*32 + nf2*16 + ln;
        int K0 = kk*32 + q*8;
        const unsigned short* vp = vT + ((size_t)b*CH + d)*(HGT*WID)
            + (sy*8 + (K0 >> 3))*WID + sx*8;
        bv[nf2] = *(const short8*)vp;
      }
#pragma unroll
      for (int mf = 0; mf < 4; mf++)
#pragma unroll
        for (int nf2 = 0; nf2 < 2; nf2++)
          facc[mf][nf2] = __builtin_amdgcn_mfma_f32_16x16x32_bf16(
              ap[mf], bv[nf2], facc[mf][nf2], 0, 0, 0);
    }
  }
#pragma unroll
  for (int mf = 0; mf < 4; mf++)
#pragma unroll
    for (int j = 0; j < 4; j++) {
      float inv = 1.f / l_run[mf][j];
      int prow = mf*16 + q*4 + j;
      size_t pg = ((size_t)b*HGT + wy*8 + (prow>>3))*WID + wx*8 + (prow&7);
      o[pg*CH + h*32 + ln]      = facc[mf][0][j] * inv;
      o[pg*CH + h*32 + 16 + ln] = facc[mf][1][j] * inv;
    }
}

// ---------------------------------------------------------------------------
// K6: o += dwconv5x5(v) + lepe_b  — LDS-staged from planar bf16 vT.
// ---------------------------------------------------------------------------
__global__ __launch_bounds__(256) void k_lepe(const unsigned short* __restrict__ vT,
    const float* __restrict__ lw, const float* __restrict__ lb,
    float* __restrict__ o) {
  __shared__ unsigned short sh[12*60*32];   // [rr][col][c] 46 KB
  int b = blockIdx.y;
  int rg = blockIdx.x >> 2, cg = blockIdx.x & 3;
  int row0 = rg*8, c0 = cg*32;
  int t = threadIdx.x;
  for (int i = t; i < 12*60*32/8; i += 256)
    ((int4*)sh)[i] = make_int4(0,0,0,0);
  __syncthreads();
  for (int i = t; i < 2688; i += 256) {
    int chunk = i % 7, rr = (i/7) % 12, c = i / 84;
    int grow = row0 + rr - 2;
    if ((unsigned)grow < HGT) {
      int4 v = *(const int4*)(vT + ((size_t)(b*CH + c0 + c))*(HGT*WID) + grow*WID + chunk*8);
      union { int4 v4; unsigned short us[8]; } u; u.v4 = v;
#pragma unroll
      for (int j = 0; j < 8; j++)
        sh[(rr*60 + 2 + chunk*8 + j)*32 + c] = u.us[j];
    }
  }
  __syncthreads();
  int c = t & 31, pg = t >> 5;
  float w[25];
#pragma unroll
  for (int i = 0; i < 25; i++) w[i] = lw[(c0 + c)*25 + i];
  float bias = lb[c0 + c];
  const unsigned short* rowp[5];
#pragma unroll
  for (int dy = 0; dy < 5; dy++) rowp[dy] = &sh[((pg + dy)*60)*32 + c];
  float win[5][5];
#pragma unroll
  for (int j = 0; j < 4; j++)
#pragma unroll
    for (int dy = 0; dy < 5; dy++) win[j][dy] = bf2f(rowp[dy][j*32]);
  float* ob = &o[(((size_t)b*HGT + row0 + pg)*WID)*CH + c0 + c];
#pragma unroll
  for (int col = 0; col < 56; col++) {
    int slot = (col + 4) % 5;
#pragma unroll
    for (int dy = 0; dy < 5; dy++) win[slot][dy] = bf2f(rowp[dy][(col + 4)*32]);
    float s = bias;
#pragma unroll
    for (int dx = 0; dx < 5; dx++) {
      int sl = (col + dx) % 5;
#pragma unroll
      for (int dy = 0; dy < 5; dy++) s += win[sl][dy] * w[dy*5 + dx];
    }
    ob[col*CH] += s;
  }
}

// ---------------------------------------------------------------------------
// K7: xh += in @ wo + wo_b  (K=128, N=128) via MFMA
// ---------------------------------------------------------------------------
__global__ __launch_bounds__(256, 2) void k_wo_mfma(
    const float* __restrict__ in, const unsigned short* __restrict__ Wt,
    const float* __restrict__ bias, float* __restrict__ xh) {
  __shared__ __align__(16) unsigned short aL[128*136];
  __shared__ __align__(16) unsigned short bL[128*136];
  size_t base = (size_t)blockIdx.x * 128;
  int t = threadIdx.x;
  {
    int r = t >> 1, half = t & 1;
    const float4* src = (const float4*)(in + (base + r)*CH + half*64);
    union { unsigned short us[8]; int4 v4; } pk;
#pragma unroll
    for (int c8 = 0; c8 < 8; c8++) {
      float4 f0 = src[c8*2], f1 = src[c8*2 + 1];
      pk.us[0] = f2bf(f0.x); pk.us[1] = f2bf(f0.y);
      pk.us[2] = f2bf(f0.z); pk.us[3] = f2bf(f0.w);
      pk.us[4] = f2bf(f1.x); pk.us[5] = f2bf(f1.y);
      pk.us[6] = f2bf(f1.z); pk.us[7] = f2bf(f1.w);
      *(int4*)&aL[r*136 + half*64 + c8*8] = pk.v4;
    }
  }
  for (int i = t; i < 2048; i += 256) {
    int row = i >> 4, seg = i & 15;
    *(int4*)&bL[row*136 + seg*8] = *(const int4*)(Wt + (size_t)row*128 + seg*8);
  }
  __syncthreads();
  int wid = t >> 6, lane = t & 63;
  int ln = lane & 15, q = lane >> 4;
  int wr = (wid >> 1)*64, wc = (wid & 1)*64;
  float4v acc[4][4];
#pragma unroll
  for (int a = 0; a < 4; a++)
#pragma unroll
    for (int b = 0; b < 4; b++)
      acc[a][b] = (float4v){0.f, 0.f, 0.f, 0.f};
#pragma unroll
  for (int kk = 0; kk < 4; kk++) {
    int ko = kk*32 + q*8;
    short8 af[4], bf[4];
#pragma unroll
    for (int mf = 0; mf < 4; mf++)
      af[mf] = *(const short8*)&aL[(wr + mf*16 + ln)*136 + ko];
#pragma unroll
    for (int nf = 0; nf < 4; nf++)
      bf[nf] = *(const short8*)&bL[(wc + nf*16 + ln)*136 + ko];
#pragma unroll
    for (int mf = 0; mf < 4; mf++)
#pragma unroll
      for (int nf = 0; nf < 4; nf++)
        acc[mf][nf] = __builtin_amdgcn_mfma_f32_16x16x32_bf16(
            af[mf], bf[nf], acc[mf][nf], 0, 0, 0);
  }
#pragma unroll
  for (int mf = 0; mf < 4; mf++)
#pragma unroll
    for (int nf = 0; nf < 4; nf++) {
      int row = wr + mf*16 + q*4;
      int col = wc + nf*16 + ln;
      float b4 = bias[col];
#pragma unroll
      for (int j = 0; j < 4; j++) {
        float* p = &xh[(base + row + j)*CH + col];
        *p += acc[mf][nf][j] + b4;
      }
    }
}

// ---------------------------------------------------------------------------
// K9: out(NCHW) = xh + hid @ mlp_w2 + mlp_b2  (K=384 in 3 chunks, N=128)
// ---------------------------------------------------------------------------
__global__ __launch_bounds__(256, 2) void k_mlp2_mfma(
    const float* __restrict__ hid, const unsigned short* __restrict__ Wt,
    const float* __restrict__ bias, const float* __restrict__ xh,
    float* __restrict__ out) {
  __shared__ __align__(16) unsigned short aL[128*136];
  __shared__ __align__(16) unsigned short bL[128*136];
  size_t base = (size_t)blockIdx.x * 128;
  int t = threadIdx.x;
  int wid = t >> 6, lane = t & 63;
  int ln = lane & 15, q = lane >> 4;
  int wr = (wid >> 1)*64, wc = (wid & 1)*64;
  float4v acc[4][4];
#pragma unroll
  for (int a = 0; a < 4; a++)
#pragma unroll
    for (int b = 0; b < 4; b++)
      acc[a][b] = (float4v){0.f, 0.f, 0.f, 0.f};
  for (int kc = 0; kc < 3; kc++) {
    if (kc) __syncthreads();
    {
      int r = t >> 1, half = t & 1;
      const float4* src = (const float4*)(hid + (base + r)*NQKV + kc*128 + half*64);
      union { unsigned short us[8]; int4 v4; } pk;
#pragma unroll
      for (int c8 = 0; c8 < 8; c8++) {
        float4 f0 = src[c8*2], f1 = src[c8*2 + 1];
        pk.us[0] = f2bf(f0.x); pk.us[1] = f2bf(f0.y);
        pk.us[2] = f2bf(f0.z); pk.us[3] = f2bf(f0.w);
        pk.us[4] = f2bf(f1.x); pk.us[5] = f2bf(f1.y);
        pk.us[6] = f2bf(f1.z); pk.us[7] = f2bf(f1.w);
        *(int4*)&aL[r*136 + half*64 + c8*8] = pk.v4;
      }
    }
    for (int i = t; i < 2048; i += 256) {
      int row = i >> 4, seg = i & 15;
      *(int4*)&bL[row*136 + seg*8] =
          *(const int4*)(Wt + (size_t)row*NQKV + kc*128 + seg*8);
    }
    __syncthreads();
#pragma unroll
    for (int kk = 0; kk < 4; kk++) {
      int ko = kk*32 + q*8;
      short8 af[4], bf[4];
#pragma unroll
      for (int mf = 0; mf < 4; mf++)
        af[mf] = *(const short8*)&aL[(wr + mf*16 + ln)*136 + ko];
#pragma unroll
      for (int nf = 0; nf < 4; nf++)
        bf[nf] = *(const short8*)&bL[(wc + nf*16 + ln)*136 + ko];
#pragma unroll
      for (int mf = 0; mf < 4; mf++)
#pragma unroll
        for (int nf = 0; nf < 4; nf++)
          acc[mf][nf] = __builtin_amdgcn_mfma_f32_16x16x32_bf16(
              af[mf], bf[nf], acc[mf][nf], 0, 0, 0);
    }
  }
#pragma unroll
  for (int mf = 0; mf < 4; mf++)
#pragma unroll
    for (int nf = 0; nf < 4; nf++) {
      int row = wr + mf*16 + q*4;
      int col = wc + nf*16 + ln;
      float b4 = bias[col];
#pragma unroll
      for (int j = 0; j < 4; j++) {
        size_t pixel = base + row + j;
        int b = (int)(pixel / (HGT*WID));
        int sp = (int)(pixel % (HGT*WID));
        out[((size_t)b*CH + col)*(HGT*WID) + sp] =
            acc[mf][nf][j] + b4 + xh[pixel*CH + col];
      }
    }
}

// ---------------------------------------------------------------------------
extern "C" void kernel_launch(void* const* d_in, const int* in_sizes, int n_in,
                              void* d_out, int out_size, void* d_ws, size_t ws_size,
                              hipStream_t stream) {
  const float* x      = (const float*)d_in[0];
  const float* pos_w  = (const float*)d_in[1];
  const float* pos_b  = (const float*)d_in[2];
  const float* ln1_g  = (const float*)d_in[3];
  const float* ln1_b  = (const float*)d_in[4];
  const float* qkv_w  = (const float*)d_in[5];
  const float* qkv_b  = (const float*)d_in[6];
  const float* lepe_w = (const float*)d_in[7];
  const float* lepe_b = (const float*)d_in[8];
  const float* wo_w   = (const float*)d_in[9];
  const float* wo_b   = (const float*)d_in[10];
  const float* ln2_g  = (const float*)d_in[11];
  const float* ln2_b  = (const float*)d_in[12];
  const float* mlp_w1 = (const float*)d_in[13];
  const float* mlp_b1 = (const float*)d_in[14];
  const float* mlp_w2 = (const float*)d_in[15];
  const float* mlp_b2 = (const float*)d_in[16];

  float* ws   = (float*)d_ws;
  float* xh   = ws;                          // NPIX*128
  float* qkv  = xh  + (size_t)NPIX*CH;       // NPIX*384
  float* o    = qkv + (size_t)NPIX*NQKV;     // NPIX*128
  float* qwin = o   + (size_t)NPIX*CH;       // B*49*128
  float* kwin = qwin + (size_t)BATCH*P2*128; // B*49*128
  int*   idx  = (int*)(kwin + (size_t)BATCH*P2*128); // B*49*4
  unsigned short* Wq = (unsigned short*)(idx + BATCH*P2*TOPK); // 384*128
  unsigned short* Wo = Wq + 384*128;         // 128*128
  unsigned short* W1 = Wo + 128*128;         // 384*128
  unsigned short* W2 = W1 + 384*128;         // 128*384
  unsigned short* vT = W2 + 128*384;         // NPIX*128 bf16
  float* hid  = qkv;                         // reuse qkv buffer for MLP hidden

  k_prep<<<1024, 128, 0, stream>>>(qkv_w, wo_w, mlp_w1, mlp_w2, Wq, Wo, W1, W2);
  k_posconv<<<dim3(28, BATCH), 256, 0, stream>>>(x, pos_w, pos_b, xh);
  k_ln_gemm_mfma<<<NPIX/128, 256, 0, stream>>>(xh, ln1_g, ln1_b, Wq, qkv_b, qkv, 0);
  k_vt<<<NPIX/32, 256, 0, stream>>>(qkv, vT);
  k_winmean<<<BATCH*P2, 256, 0, stream>>>(qkv, qwin, kwin);
  k_topk<<<BATCH, 64, 0, stream>>>(qwin, kwin, idx);
  k_attn_mfma<<<BATCH*P2, 256, 0, stream>>>(qkv, vT, idx, o);
  k_lepe<<<dim3(28, BATCH), 256, 0, stream>>>(vT, lepe_w, lepe_b, o);
  k_wo_mfma<<<NPIX/128, 256, 0, stream>>>(o, Wo, wo_b, xh);
  k_ln_gemm_mfma<<<NPIX/128, 256, 0, stream>>>(xh, ln2_g, ln2_b, W1, mlp_b1, hid, 1);
  k_mlp2_mfma<<<NPIX/128, 256, 0, stream>>>(hid, W2, mlp_b2, xh, (float*)d_out);
}

// Round 6
// 399.611 us; speedup vs baseline: 3.5895x; 1.1914x over previous
//
#include <hip/hip_runtime.h>
#include <math.h>

#define BATCH 16
#define CH    128
#define HGT   56
#define WID   56
#define NPIX  (BATCH*HGT*WID)   // 50176
#define NQKV  384
#define NWIN  7
#define P2    49
#define TOPK  4
#define ATT_SCALE 0.088388347648318447f   // 128^-0.5

typedef __attribute__((ext_vector_type(8))) short short8;
typedef __attribute__((ext_vector_type(4))) float float4v;

static __device__ __forceinline__ unsigned short f2bf(float f) {
  unsigned u = __float_as_uint(f);
  u += 0x7fffu + ((u >> 16) & 1u);   // round-to-nearest-even
  return (unsigned short)(u >> 16);
}
static __device__ __forceinline__ float bf2f(unsigned short u) {
  return __uint_as_float((unsigned)u << 16);
}

static __device__ __forceinline__ short8 cvt8(float4 a, float4 b) {
  union { unsigned short us[8]; short8 s8; } u;
  u.us[0] = f2bf(a.x); u.us[1] = f2bf(a.y); u.us[2] = f2bf(a.z); u.us[3] = f2bf(a.w);
  u.us[4] = f2bf(b.x); u.us[5] = f2bf(b.y); u.us[6] = f2bf(b.z); u.us[7] = f2bf(b.w);
  return u.s8;
}

// ---------------------------------------------------------------------------
// K0: weight prep — convert to bf16 and transpose to [N][K] layout.
// ---------------------------------------------------------------------------
__global__ __launch_bounds__(128) void k_prep(
    const float* __restrict__ qkv_w, const float* __restrict__ wo_w,
    const float* __restrict__ mlp_w1, const float* __restrict__ mlp_w2,
    unsigned short* __restrict__ Wq, unsigned short* __restrict__ Wo,
    unsigned short* __restrict__ W1, unsigned short* __restrict__ W2) {
  int bx = blockIdx.x, t = threadIdx.x;
  if (bx < 384) {
    int n = bx;
    Wq[n*128 + t] = f2bf(qkv_w[(size_t)t*384 + n]);
  } else if (bx < 512) {
    int n = bx - 384;
    Wo[n*128 + t] = f2bf(wo_w[(size_t)t*128 + n]);
  } else if (bx < 896) {
    int n = bx - 512;
    W1[n*128 + t] = f2bf(mlp_w1[(size_t)t*384 + n]);
  } else {
    int n = bx - 896;
    for (int k = t; k < 384; k += 128)
      W2[n*384 + k] = f2bf(mlp_w2[(size_t)k*128 + n]);
  }
}

// ---------------------------------------------------------------------------
// K1: x(NCHW) -> xh(NHWC) = x + dwconv3x3(x).  LDS-staged transpose.
// ---------------------------------------------------------------------------
__global__ __launch_bounds__(256) void k_posconv(const float* __restrict__ x,
    const float* __restrict__ pw, const float* __restrict__ pb,
    float* __restrict__ xh) {
  __shared__ float sh[10*58*32];   // [rr][colidx][c], colidx 0 = global col -1
  int b = blockIdx.y;
  int rg = blockIdx.x >> 2, cg = blockIdx.x & 3;
  int row0 = rg*8, c0 = cg*32;
  int t = threadIdx.x;
  for (int i = t; i < 10*58*32/4; i += 256)
    ((int4*)sh)[i] = make_int4(0,0,0,0);
  __syncthreads();
  for (int i = t; i < 4480; i += 256) {
    int c = i & 31, chunk = (i >> 5) % 14, rr = i / 448;
    int grow = row0 + rr - 1;
    if ((unsigned)grow < HGT) {
      float4 v = *(const float4*)(x + ((size_t)(b*CH + c0 + c))*(HGT*WID)
                                  + grow*WID + chunk*4);
      float* d = &sh[(rr*58 + 1 + chunk*4)*32 + c];
      d[0] = v.x; d[32] = v.y; d[64] = v.z; d[96] = v.w;
    }
  }
  __syncthreads();
  int c = t & 31, pg = t >> 5;
  float w[9];
#pragma unroll
  for (int i = 0; i < 9; i++) w[i] = pw[(c0 + c)*9 + i];
  float bias = pb[c0 + c];
  const float* rowp[3];
#pragma unroll
  for (int dy = 0; dy < 3; dy++) rowp[dy] = &sh[((pg + dy)*58)*32 + c];
  float win[3][3];
#pragma unroll
  for (int j = 0; j < 2; j++)
#pragma unroll
    for (int dy = 0; dy < 3; dy++) win[j][dy] = rowp[dy][j*32];
  float* ob = &xh[(((size_t)b*HGT + row0 + pg)*WID)*CH + c0 + c];
#pragma unroll
  for (int col = 0; col < 56; col++) {
    int slot = (col + 2) % 3;
#pragma unroll
    for (int dy = 0; dy < 3; dy++) win[slot][dy] = rowp[dy][(col + 2)*32];
    float s = bias + win[(col + 1) % 3][1];   // + x (center)
#pragma unroll
    for (int dx = 0; dx < 3; dx++) {
      int sl = (col + dx) % 3;
#pragma unroll
      for (int dy = 0; dy < 3; dy++) s += win[sl][dy] * w[dy*3 + dx];
    }
    ob[col*CH] = s;
  }
}

// ---------------------------------------------------------------------------
// K2/K8: fused LN + MFMA GEMM. M-tile 128, N=384 (3 chunks of 128), K=128.
// ---------------------------------------------------------------------------
__global__ __launch_bounds__(256, 2) void k_ln_gemm_mfma(
    const float* __restrict__ in, const float* __restrict__ g,
    const float* __restrict__ be, const unsigned short* __restrict__ Wt,
    const float* __restrict__ bias, float* __restrict__ out, int do_gelu) {
  __shared__ __align__(16) unsigned short aL[128*136];
  __shared__ __align__(16) unsigned short bL[128*136];
  size_t base = (size_t)blockIdx.x * 128;
  int t = threadIdx.x;
  { // ---- LN + A-stage ----
    int r = t >> 1, half = t & 1;
    const float4* src = (const float4*)(in + (base + r)*CH + half*64);
    float v[64];
    float s = 0.f, ss = 0.f;
#pragma unroll
    for (int i = 0; i < 16; i++) {
      float4 f = src[i];
      v[4*i] = f.x; v[4*i+1] = f.y; v[4*i+2] = f.z; v[4*i+3] = f.w;
      s += f.x + f.y + f.z + f.w;
      ss += f.x*f.x + f.y*f.y + f.z*f.z + f.w*f.w;
    }
    s += __shfl_xor(s, 1); ss += __shfl_xor(ss, 1);
    float m  = s * (1.f/128.f);
    float var = ss * (1.f/128.f) - m*m;
    float rs = rsqrtf(var + 1e-6f);
    union { unsigned short us[8]; int4 v4; } pk;
#pragma unroll
    for (int c8 = 0; c8 < 8; c8++) {
#pragma unroll
      for (int j = 0; j < 8; j++) {
        int ch = half*64 + c8*8 + j;
        pk.us[j] = f2bf((v[c8*8 + j] - m) * rs * g[ch] + be[ch]);
      }
      *(int4*)&aL[r*136 + half*64 + c8*8] = pk.v4;
    }
  }
  int wid = t >> 6, lane = t & 63;
  int ln = lane & 15, q = lane >> 4;
  int wr = (wid >> 1)*64, wc = (wid & 1)*64;
  for (int chunk = 0; chunk < 3; chunk++) {
    if (chunk) __syncthreads();
    for (int i = t; i < 2048; i += 256) {
      int row = i >> 4, seg = i & 15;
      *(int4*)&bL[row*136 + seg*8] =
          *(const int4*)(Wt + (size_t)(chunk*128 + row)*128 + seg*8);
    }
    __syncthreads();
    float4v acc[4][4];
#pragma unroll
    for (int a = 0; a < 4; a++)
#pragma unroll
      for (int b = 0; b < 4; b++)
        acc[a][b] = (float4v){0.f, 0.f, 0.f, 0.f};
#pragma unroll
    for (int kk = 0; kk < 4; kk++) {
      int ko = kk*32 + q*8;
      short8 af[4], bf[4];
#pragma unroll
      for (int mf = 0; mf < 4; mf++)
        af[mf] = *(const short8*)&aL[(wr + mf*16 + ln)*136 + ko];
#pragma unroll
      for (int nf = 0; nf < 4; nf++)
        bf[nf] = *(const short8*)&bL[(wc + nf*16 + ln)*136 + ko];
#pragma unroll
      for (int mf = 0; mf < 4; mf++)
#pragma unroll
        for (int nf = 0; nf < 4; nf++)
          acc[mf][nf] = __builtin_amdgcn_mfma_f32_16x16x32_bf16(
              af[mf], bf[nf], acc[mf][nf], 0, 0, 0);
    }
#pragma unroll
    for (int mf = 0; mf < 4; mf++)
#pragma unroll
      for (int nf = 0; nf < 4; nf++) {
        int row = wr + mf*16 + q*4;
        int col = wc + nf*16 + ln + chunk*128;
        float b4 = bias[col];
#pragma unroll
        for (int j = 0; j < 4; j++) {
          float vv = acc[mf][nf][j] + b4;
          if (do_gelu) vv = 0.5f * vv * (1.f + erff(vv * 0.70710678118654752f));
          out[(base + row + j)*NQKV + col] = vv;
        }
      }
  }
}

// ---------------------------------------------------------------------------
// K_vt: vT[b][c][hw] bf16  <- qkv cols [256,384) (LDS-tiled transpose)
// ---------------------------------------------------------------------------
__global__ __launch_bounds__(256) void k_vt(const float* __restrict__ qkv,
    unsigned short* __restrict__ vT) {
  __shared__ unsigned short tile[128*40];
  int pg0 = blockIdx.x * 32;
  int b = pg0 / (HGT*WID), sp0 = pg0 % (HGT*WID);
  int t = threadIdx.x;
  {
    int pl = t >> 3, cg = t & 7;
    const float4* src = (const float4*)(qkv + (size_t)(pg0 + pl)*NQKV + 256 + cg*16);
#pragma unroll
    for (int i = 0; i < 4; i++) {
      float4 f = src[i];
      int c = cg*16 + i*4;
      tile[(c+0)*40 + pl] = f2bf(f.x);
      tile[(c+1)*40 + pl] = f2bf(f.y);
      tile[(c+2)*40 + pl] = f2bf(f.z);
      tile[(c+3)*40 + pl] = f2bf(f.w);
    }
  }
  __syncthreads();
  int c = t >> 1, half = t & 1;
  unsigned short* dst = vT + ((size_t)b*CH + c)*(HGT*WID) + sp0 + half*16;
  const int4* srcl = (const int4*)&tile[c*40 + half*16];
  ((int4*)dst)[0] = srcl[0];
  ((int4*)dst)[1] = srcl[1];
}

// ---------------------------------------------------------------------------
// K3: window means — wave-wide float4 loads, LDS cross-wave sum
// ---------------------------------------------------------------------------
__global__ __launch_bounds__(256) void k_winmean(const float* __restrict__ qkv,
    float* __restrict__ qwin, float* __restrict__ kwin) {
  __shared__ float4 red[4][64];
  int bp = blockIdx.x; int b = bp / P2, p = bp % P2;
  int wy = p / NWIN, wx = p % NWIN;
  int w = threadIdx.x >> 6, l = threadIdx.x & 63;
  float4 acc = make_float4(0.f, 0.f, 0.f, 0.f);
#pragma unroll
  for (int i = 0; i < 16; i++) {
    int pix = w*16 + i;
    int ir = pix >> 3, iw = pix & 7;
    size_t po = (((size_t)b*HGT + wy*8 + ir)*WID + wx*8 + iw)*NQKV;
    float4 v = ((const float4*)(qkv + po))[l];
    acc.x += v.x; acc.y += v.y; acc.z += v.z; acc.w += v.w;
  }
  red[w][l] = acc;
  __syncthreads();
  if (w == 0) {
    float4 t0 = red[0][l], t1 = red[1][l], t2 = red[2][l], t3 = red[3][l];
    float4 s = make_float4((t0.x+t1.x+t2.x+t3.x)*(1.f/64.f),
                           (t0.y+t1.y+t2.y+t3.y)*(1.f/64.f),
                           (t0.z+t1.z+t2.z+t3.z)*(1.f/64.f),
                           (t0.w+t1.w+t2.w+t3.w)*(1.f/64.f));
    if (l < 32) ((float4*)(qwin + (size_t)bp*128))[l] = s;
    else        ((float4*)(kwin + (size_t)bp*128))[l - 32] = s;
  }
}

// ---------------------------------------------------------------------------
// K4: routing logits + top-4.  One block per (b, query window): 784 blocks.
// thread = (key window, quarter of 128 ch); shfl-reduce quarters -> LDS;
// single-thread top-4 on 49 values (tie-break lowest index, = jax top_k).
// ---------------------------------------------------------------------------
__global__ __launch_bounds__(256) void k_topk(const float* __restrict__ qwin,
    const float* __restrict__ kwin, int* __restrict__ idx) {
  __shared__ float logits[64];
  int bp = blockIdx.x; int b = bp / P2;
  int t = threadIdx.x;
  int key = t >> 2, qu = t & 3;
  float s = 0.f;
  if (key < P2) {
    const float4* qp = (const float4*)(qwin + (size_t)bp*128 + qu*32);
    const float4* kp = (const float4*)(kwin + ((size_t)b*P2 + key)*128 + qu*32);
#pragma unroll
    for (int i = 0; i < 8; i++) {
      float4 qv = qp[i], kv = kp[i];
      s += qv.x*kv.x + qv.y*kv.y + qv.z*kv.z + qv.w*kv.w;
    }
  }
  s += __shfl_xor(s, 1);
  s += __shfl_xor(s, 2);
  if (qu == 0 && key < P2) logits[key] = s;
  __syncthreads();
  if (t == 0) {
    unsigned long long used = 0ULL;
    for (int tt = 0; tt < TOPK; tt++) {
      float best = -1e30f; int bi = 0;
      for (int q = 0; q < P2; q++) {
        bool ok = !((used >> q) & 1ULL);
        float lv = logits[q];
        if (ok && lv > best) { best = lv; bi = q; }
      }
      used |= 1ULL << bi;
      idx[(size_t)bp*TOPK + tt] = bi;
    }
  }
}

// ---------------------------------------------------------------------------
// K5: MFMA attention
// ---------------------------------------------------------------------------
#define PLS 72
__global__ __launch_bounds__(256) void k_attn_mfma(
    const float* __restrict__ qkv, const unsigned short* __restrict__ vT,
    const int* __restrict__ idx, float* __restrict__ o) {
  __shared__ unsigned short pL[4][64*PLS];
  int bp = blockIdx.x; int b = bp / P2, p = bp % P2;
  int wy = p / NWIN, wx = p % NWIN;
  int h = threadIdx.x >> 6, lane = threadIdx.x & 63;
  int ln = lane & 15, q = lane >> 4;

  short8 aq[4];
#pragma unroll
  for (int mf = 0; mf < 4; mf++) {
    int pq = mf*16 + ln;
    const float* qp = qkv + (((size_t)b*HGT + wy*8 + (pq>>3))*WID + wx*8 + (pq&7))*NQKV + h*32 + q*8;
    float4 f0 = *(const float4*)qp, f1 = *(const float4*)(qp + 4);
    f0.x *= ATT_SCALE; f0.y *= ATT_SCALE; f0.z *= ATT_SCALE; f0.w *= ATT_SCALE;
    f1.x *= ATT_SCALE; f1.y *= ATT_SCALE; f1.z *= ATT_SCALE; f1.w *= ATT_SCALE;
    aq[mf] = cvt8(f0, f1);
  }

  float m_run[4][4], l_run[4][4];
  float4v facc[4][2];
#pragma unroll
  for (int mf = 0; mf < 4; mf++) {
#pragma unroll
    for (int j = 0; j < 4; j++) { m_run[mf][j] = -1e30f; l_run[mf][j] = 0.f; }
    facc[mf][0] = (float4v){0.f,0.f,0.f,0.f};
    facc[mf][1] = (float4v){0.f,0.f,0.f,0.f};
  }

  unsigned short* myP = &pL[h][0];
  int swr = ((ln >> 2) & 3) * 16;

  for (int r = 0; r < TOPK; r++) {
    int win = idx[(size_t)bp*TOPK + r];
    int sy = win / NWIN, sx = win % NWIN;
    short8 bk[4];
#pragma unroll
    for (int nf = 0; nf < 4; nf++) {
      int kp = nf*16 + ln;
      const float* kpp = qkv + (((size_t)b*HGT + sy*8 + (kp>>3))*WID + sx*8 + (kp&7))*NQKV + 128 + h*32 + q*8;
      bk[nf] = cvt8(*(const float4*)kpp, *(const float4*)(kpp + 4));
    }
    float4v sacc[4][4];
#pragma unroll
    for (int mf = 0; mf < 4; mf++)
#pragma unroll
      for (int nf = 0; nf < 4; nf++)
        sacc[mf][nf] = (float4v){0.f,0.f,0.f,0.f};
#pragma unroll
    for (int mf = 0; mf < 4; mf++)
#pragma unroll
      for (int nf = 0; nf < 4; nf++)
        sacc[mf][nf] = __builtin_amdgcn_mfma_f32_16x16x32_bf16(
            aq[mf], bk[nf], sacc[mf][nf], 0, 0, 0);
#pragma unroll
    for (int mf = 0; mf < 4; mf++) {
#pragma unroll
      for (int j = 0; j < 4; j++) {
        float s0 = sacc[mf][0][j], s1 = sacc[mf][1][j];
        float s2 = sacc[mf][2][j], s3 = sacc[mf][3][j];
        float mx = fmaxf(fmaxf(s0, s1), fmaxf(s2, s3));
        mx = fmaxf(mx, __shfl_xor(mx, 1));
        mx = fmaxf(mx, __shfl_xor(mx, 2));
        mx = fmaxf(mx, __shfl_xor(mx, 4));
        mx = fmaxf(mx, __shfl_xor(mx, 8));
        float mo = m_run[mf][j];
        float mn = fmaxf(mo, mx);
        float corr = __expf(mo - mn);
        m_run[mf][j] = mn;
        float e0 = __expf(s0 - mn), e1 = __expf(s1 - mn);
        float e2 = __expf(s2 - mn), e3 = __expf(s3 - mn);
        float ls = e0 + e1 + e2 + e3;
        ls += __shfl_xor(ls, 1);
        ls += __shfl_xor(ls, 2);
        ls += __shfl_xor(ls, 4);
        ls += __shfl_xor(ls, 8);
        l_run[mf][j] = l_run[mf][j]*corr + ls;
        facc[mf][0][j] *= corr; facc[mf][1][j] *= corr;
        int rowoff = (mf*16 + q*4 + j)*PLS;
        int sww = q*16;
        myP[rowoff + (( 0 + ln) ^ sww)] = f2bf(e0);
        myP[rowoff + ((16 + ln) ^ sww)] = f2bf(e1);
        myP[rowoff + ((32 + ln) ^ sww)] = f2bf(e2);
        myP[rowoff + ((48 + ln) ^ sww)] = f2bf(e3);
      }
    }
#pragma unroll
    for (int kk = 0; kk < 2; kk++) {
      short8 ap[4];
#pragma unroll
      for (int mf = 0; mf < 4; mf++)
        ap[mf] = *(const short8*)&myP[(mf*16 + ln)*PLS + ((kk*32 + q*8) ^ swr)];
      short8 bv[2];
#pragma unroll
      for (int nf2 = 0; nf2 < 2; nf2++) {
        int d = h*32 + nf2*16 + ln;
        int K0 = kk*32 + q*8;
        const unsigned short* vp = vT + ((size_t)b*CH + d)*(HGT*WID)
            + (sy*8 + (K0 >> 3))*WID + sx*8;
        bv[nf2] = *(const short8*)vp;
      }
#pragma unroll
      for (int mf = 0; mf < 4; mf++)
#pragma unroll
        for (int nf2 = 0; nf2 < 2; nf2++)
          facc[mf][nf2] = __builtin_amdgcn_mfma_f32_16x16x32_bf16(
              ap[mf], bv[nf2], facc[mf][nf2], 0, 0, 0);
    }
  }
#pragma unroll
  for (int mf = 0; mf < 4; mf++)
#pragma unroll
    for (int j = 0; j < 4; j++) {
      float inv = 1.f / l_run[mf][j];
      int prow = mf*16 + q*4 + j;
      size_t pg = ((size_t)b*HGT + wy*8 + (prow>>3))*WID + wx*8 + (prow&7);
      o[pg*CH + h*32 + ln]      = facc[mf][0][j] * inv;
      o[pg*CH + h*32 + 16 + ln] = facc[mf][1][j] * inv;
    }
}

// ---------------------------------------------------------------------------
// K6: o += dwconv5x5(v) + lepe_b  — LDS-staged from planar bf16 vT.
// ---------------------------------------------------------------------------
__global__ __launch_bounds__(256) void k_lepe(const unsigned short* __restrict__ vT,
    const float* __restrict__ lw, const float* __restrict__ lb,
    float* __restrict__ o) {
  __shared__ unsigned short sh[12*60*32];   // [rr][col][c] 46 KB
  int b = blockIdx.y;
  int rg = blockIdx.x >> 2, cg = blockIdx.x & 3;
  int row0 = rg*8, c0 = cg*32;
  int t = threadIdx.x;
  for (int i = t; i < 12*60*32/8; i += 256)
    ((int4*)sh)[i] = make_int4(0,0,0,0);
  __syncthreads();
  for (int i = t; i < 2688; i += 256) {
    int chunk = i % 7, rr = (i/7) % 12, c = i / 84;
    int grow = row0 + rr - 2;
    if ((unsigned)grow < HGT) {
      int4 v = *(const int4*)(vT + ((size_t)(b*CH + c0 + c))*(HGT*WID) + grow*WID + chunk*8);
      union { int4 v4; unsigned short us[8]; } u; u.v4 = v;
#pragma unroll
      for (int j = 0; j < 8; j++)
        sh[(rr*60 + 2 + chunk*8 + j)*32 + c] = u.us[j];
    }
  }
  __syncthreads();
  int c = t & 31, pg = t >> 5;
  float w[25];
#pragma unroll
  for (int i = 0; i < 25; i++) w[i] = lw[(c0 + c)*25 + i];
  float bias = lb[c0 + c];
  const unsigned short* rowp[5];
#pragma unroll
  for (int dy = 0; dy < 5; dy++) rowp[dy] = &sh[((pg + dy)*60)*32 + c];
  float win[5][5];
#pragma unroll
  for (int j = 0; j < 4; j++)
#pragma unroll
    for (int dy = 0; dy < 5; dy++) win[j][dy] = bf2f(rowp[dy][j*32]);
  float* ob = &o[(((size_t)b*HGT + row0 + pg)*WID)*CH + c0 + c];
#pragma unroll
  for (int col = 0; col < 56; col++) {
    int slot = (col + 4) % 5;
#pragma unroll
    for (int dy = 0; dy < 5; dy++) win[slot][dy] = bf2f(rowp[dy][(col + 4)*32]);
    float s = bias;
#pragma unroll
    for (int dx = 0; dx < 5; dx++) {
      int sl = (col + dx) % 5;
#pragma unroll
      for (int dy = 0; dy < 5; dy++) s += win[sl][dy] * w[dy*5 + dx];
    }
    ob[col*CH] += s;
  }
}

// ---------------------------------------------------------------------------
// K7: xh += in @ wo + wo_b  (K=128, N=128) via MFMA
// ---------------------------------------------------------------------------
__global__ __launch_bounds__(256, 2) void k_wo_mfma(
    const float* __restrict__ in, const unsigned short* __restrict__ Wt,
    const float* __restrict__ bias, float* __restrict__ xh) {
  __shared__ __align__(16) unsigned short aL[128*136];
  __shared__ __align__(16) unsigned short bL[128*136];
  size_t base = (size_t)blockIdx.x * 128;
  int t = threadIdx.x;
  {
    int r = t >> 1, half = t & 1;
    const float4* src = (const float4*)(in + (base + r)*CH + half*64);
    union { unsigned short us[8]; int4 v4; } pk;
#pragma unroll
    for (int c8 = 0; c8 < 8; c8++) {
      float4 f0 = src[c8*2], f1 = src[c8*2 + 1];
      pk.us[0] = f2bf(f0.x); pk.us[1] = f2bf(f0.y);
      pk.us[2] = f2bf(f0.z); pk.us[3] = f2bf(f0.w);
      pk.us[4] = f2bf(f1.x); pk.us[5] = f2bf(f1.y);
      pk.us[6] = f2bf(f1.z); pk.us[7] = f2bf(f1.w);
      *(int4*)&aL[r*136 + half*64 + c8*8] = pk.v4;
    }
  }
  for (int i = t; i < 2048; i += 256) {
    int row = i >> 4, seg = i & 15;
    *(int4*)&bL[row*136 + seg*8] = *(const int4*)(Wt + (size_t)row*128 + seg*8);
  }
  __syncthreads();
  int wid = t >> 6, lane = t & 63;
  int ln = lane & 15, q = lane >> 4;
  int wr = (wid >> 1)*64, wc = (wid & 1)*64;
  float4v acc[4][4];
#pragma unroll
  for (int a = 0; a < 4; a++)
#pragma unroll
    for (int b = 0; b < 4; b++)
      acc[a][b] = (float4v){0.f, 0.f, 0.f, 0.f};
#pragma unroll
  for (int kk = 0; kk < 4; kk++) {
    int ko = kk*32 + q*8;
    short8 af[4], bf[4];
#pragma unroll
    for (int mf = 0; mf < 4; mf++)
      af[mf] = *(const short8*)&aL[(wr + mf*16 + ln)*136 + ko];
#pragma unroll
    for (int nf = 0; nf < 4; nf++)
      bf[nf] = *(const short8*)&bL[(wc + nf*16 + ln)*136 + ko];
#pragma unroll
    for (int mf = 0; mf < 4; mf++)
#pragma unroll
      for (int nf = 0; nf < 4; nf++)
        acc[mf][nf] = __builtin_amdgcn_mfma_f32_16x16x32_bf16(
            af[mf], bf[nf], acc[mf][nf], 0, 0, 0);
  }
#pragma unroll
  for (int mf = 0; mf < 4; mf++)
#pragma unroll
    for (int nf = 0; nf < 4; nf++) {
      int row = wr + mf*16 + q*4;
      int col = wc + nf*16 + ln;
      float b4 = bias[col];
#pragma unroll
      for (int j = 0; j < 4; j++) {
        float* p = &xh[(base + row + j)*CH + col];
        *p += acc[mf][nf][j] + b4;
      }
    }
}

// ---------------------------------------------------------------------------
// K9: out(NCHW) = xh + hid @ mlp_w2 + mlp_b2  (K=384 in 3 chunks, N=128)
// ---------------------------------------------------------------------------
__global__ __launch_bounds__(256, 2) void k_mlp2_mfma(
    const float* __restrict__ hid, const unsigned short* __restrict__ Wt,
    const float* __restrict__ bias, const float* __restrict__ xh,
    float* __restrict__ out) {
  __shared__ __align__(16) unsigned short aL[128*136];
  __shared__ __align__(16) unsigned short bL[128*136];
  size_t base = (size_t)blockIdx.x * 128;
  int t = threadIdx.x;
  int wid = t >> 6, lane = t & 63;
  int ln = lane & 15, q = lane >> 4;
  int wr = (wid >> 1)*64, wc = (wid & 1)*64;
  float4v acc[4][4];
#pragma unroll
  for (int a = 0; a < 4; a++)
#pragma unroll
    for (int b = 0; b < 4; b++)
      acc[a][b] = (float4v){0.f, 0.f, 0.f, 0.f};
  for (int kc = 0; kc < 3; kc++) {
    if (kc) __syncthreads();
    {
      int r = t >> 1, half = t & 1;
      const float4* src = (const float4*)(hid + (base + r)*NQKV + kc*128 + half*64);
      union { unsigned short us[8]; int4 v4; } pk;
#pragma unroll
      for (int c8 = 0; c8 < 8; c8++) {
        float4 f0 = src[c8*2], f1 = src[c8*2 + 1];
        pk.us[0] = f2bf(f0.x); pk.us[1] = f2bf(f0.y);
        pk.us[2] = f2bf(f0.z); pk.us[3] = f2bf(f0.w);
        pk.us[4] = f2bf(f1.x); pk.us[5] = f2bf(f1.y);
        pk.us[6] = f2bf(f1.z); pk.us[7] = f2bf(f1.w);
        *(int4*)&aL[r*136 + half*64 + c8*8] = pk.v4;
      }
    }
    for (int i = t; i < 2048; i += 256) {
      int row = i >> 4, seg = i & 15;
      *(int4*)&bL[row*136 + seg*8] =
          *(const int4*)(Wt + (size_t)row*NQKV + kc*128 + seg*8);
    }
    __syncthreads();
#pragma unroll
    for (int kk = 0; kk < 4; kk++) {
      int ko = kk*32 + q*8;
      short8 af[4], bf[4];
#pragma unroll
      for (int mf = 0; mf < 4; mf++)
        af[mf] = *(const short8*)&aL[(wr + mf*16 + ln)*136 + ko];
#pragma unroll
      for (int nf = 0; nf < 4; nf++)
        bf[nf] = *(const short8*)&bL[(wc + nf*16 + ln)*136 + ko];
#pragma unroll
      for (int mf = 0; mf < 4; mf++)
#pragma unroll
        for (int nf = 0; nf < 4; nf++)
          acc[mf][nf] = __builtin_amdgcn_mfma_f32_16x16x32_bf16(
              af[mf], bf[nf], acc[mf][nf], 0, 0, 0);
    }
  }
#pragma unroll
  for (int mf = 0; mf < 4; mf++)
#pragma unroll
    for (int nf = 0; nf < 4; nf++) {
      int row = wr + mf*16 + q*4;
      int col = wc + nf*16 + ln;
      float b4 = bias[col];
#pragma unroll
      for (int j = 0; j < 4; j++) {
        size_t pixel = base + row + j;
        int b = (int)(pixel / (HGT*WID));
        int sp = (int)(pixel % (HGT*WID));
        out[((size_t)b*CH + col)*(HGT*WID) + sp] =
            acc[mf][nf][j] + b4 + xh[pixel*CH + col];
      }
    }
}

// ---------------------------------------------------------------------------
extern "C" void kernel_launch(void* const* d_in, const int* in_sizes, int n_in,
                              void* d_out, int out_size, void* d_ws, size_t ws_size,
                              hipStream_t stream) {
  const float* x      = (const float*)d_in[0];
  const float* pos_w  = (const float*)d_in[1];
  const float* pos_b  = (const float*)d_in[2];
  const float* ln1_g  = (const float*)d_in[3];
  const float* ln1_b  = (const float*)d_in[4];
  const float* qkv_w  = (const float*)d_in[5];
  const float* qkv_b  = (const float*)d_in[6];
  const float* lepe_w = (const float*)d_in[7];
  const float* lepe_b = (const float*)d_in[8];
  const float* wo_w   = (const float*)d_in[9];
  const float* wo_b   = (const float*)d_in[10];
  const float* ln2_g  = (const float*)d_in[11];
  const float* ln2_b  = (const float*)d_in[12];
  const float* mlp_w1 = (const float*)d_in[13];
  const float* mlp_b1 = (const float*)d_in[14];
  const float* mlp_w2 = (const float*)d_in[15];
  const float* mlp_b2 = (const float*)d_in[16];

  float* ws   = (float*)d_ws;
  float* xh   = ws;                          // NPIX*128
  float* qkv  = xh  + (size_t)NPIX*CH;       // NPIX*384
  float* o    = qkv + (size_t)NPIX*NQKV;     // NPIX*128
  float* qwin = o   + (size_t)NPIX*CH;       // B*49*128
  float* kwin = qwin + (size_t)BATCH*P2*128; // B*49*128
  int*   idx  = (int*)(kwin + (size_t)BATCH*P2*128); // B*49*4
  unsigned short* Wq = (unsigned short*)(idx + BATCH*P2*TOPK); // 384*128
  unsigned short* Wo = Wq + 384*128;         // 128*128
  unsigned short* W1 = Wo + 128*128;         // 384*128
  unsigned short* W2 = W1 + 384*128;         // 128*384
  unsigned short* vT = W2 + 128*384;         // NPIX*128 bf16
  float* hid  = qkv;                         // reuse qkv buffer for MLP hidden

  k_prep<<<1024, 128, 0, stream>>>(qkv_w, wo_w, mlp_w1, mlp_w2, Wq, Wo, W1, W2);
  k_posconv<<<dim3(28, BATCH), 256, 0, stream>>>(x, pos_w, pos_b, xh);
  k_ln_gemm_mfma<<<NPIX/128, 256, 0, stream>>>(xh, ln1_g, ln1_b, Wq, qkv_b, qkv, 0);
  k_vt<<<NPIX/32, 256, 0, stream>>>(qkv, vT);
  k_winmean<<<BATCH*P2, 256, 0, stream>>>(qkv, qwin, kwin);
  k_topk<<<BATCH*P2, 256, 0, stream>>>(qwin, kwin, idx);
  k_attn_mfma<<<BATCH*P2, 256, 0, stream>>>(qkv, vT, idx, o);
  k_lepe<<<dim3(28, BATCH), 256, 0, stream>>>(vT, lepe_w, lepe_b, o);
  k_wo_mfma<<<NPIX/128, 256, 0, stream>>>(o, Wo, wo_b, xh);
  k_ln_gemm_mfma<<<NPIX/128, 256, 0, stream>>>(xh, ln2_g, ln2_b, W1, mlp_b1, hid, 1);
  k_mlp2_mfma<<<NPIX/128, 256, 0, stream>>>(hid, W2, mlp_b2, xh, (float*)d_out);
}